// Round 15
// baseline (248.220 us; speedup 1.0000x reference)
//
#include <hip/hip_runtime.h>
#include <hip/hip_bf16.h>
#include <float.h>
#include <math.h>

#define NN   50000
#define BB   50
#define NPGc 1000
#define EE   300000
#define HH   256
#define FIN  79
#define KK   500
#define GR   32      // gemm rows per block
#define APAD 264     // gemm2 A-plane LDS row stride in ushorts (256 + 8 pad)
#define APAD1 104    // layer1 c-plane LDS row stride in ushorts (96 + 8 pad)

typedef __hip_bfloat16 bf16;
typedef float v2f __attribute__((ext_vector_type(2)));
typedef short short8 __attribute__((ext_vector_type(8)));
typedef float f32x4 __attribute__((ext_vector_type(4)));

__device__ __forceinline__ float bfbits(unsigned short h) {
    return __uint_as_float(((unsigned int)h) << 16);
}
__device__ __forceinline__ float ldf(const void* p, int i, bool f32) {
    return f32 ? ((const float*)p)[i] : bfbits(((const unsigned short*)p)[i]);
}
__device__ __forceinline__ float4 ldf4(const void* p, int i, bool f32) {
    if (f32) return ((const float4*)p)[i >> 2];
    ushort4 u = ((const ushort4*)p)[i >> 2];
    return make_float4(bfbits(u.x), bfbits(u.y), bfbits(u.z), bfbits(u.w));
}
__device__ __forceinline__ int   rli(int v, int q) {
    return __builtin_amdgcn_readlane(v, q);
}
__device__ __forceinline__ float rlf(float v, int q) {
    return __int_as_float(__builtin_amdgcn_readlane(__float_as_int(v), q));
}
// fp32 -> 3 bf16 planes (RNE at each step; residuals exact) ~2^-24 total error
__device__ __forceinline__ void split3(float a, unsigned short& h,
                                       unsigned short& m, unsigned short& l) {
    unsigned int u = __float_as_uint(a);
    h = (unsigned short)((u + 0x7FFFu + ((u >> 16) & 1u)) >> 16);
    float r1 = a - bfbits(h);
    u = __float_as_uint(r1);
    m = (unsigned short)((u + 0x7FFFu + ((u >> 16) & 1u)) >> 16);
    float r2 = r1 - bfbits(m);
    u = __float_as_uint(r2);
    l = (unsigned short)((u + 0x7FFFu + ((u >> 16) & 1u)) >> 16);
}

// ---------------- count (+ dtype detect in the extra block) ----------------
// Also records each edge's intra-bucket position so k_fill needs no atomics.

__global__ void k_count(const int* __restrict__ edst, int* __restrict__ deg,
                        int* __restrict__ pose,
                        const unsigned int* __restrict__ w1, int* __restrict__ flag) {
    int t = threadIdx.x;
    if (blockIdx.x == gridDim.x - 1) {
        __shared__ int sm[256];
        int c = 0;
        for (int i = t; i < 10112; i += 256) {
            unsigned int e = (w1[i] >> 7) & 0xFFu;
            c += (e >= 128u) ? 1 : 0;
        }
        sm[t] = c;
        __syncthreads();
        for (int off = 128; off > 0; off >>= 1) {
            if (t < off) sm[t] += sm[t + off];
            __syncthreads();
        }
        if (t == 0) flag[0] = (sm[0] > 500) ? 1 : 0;
        return;
    }
    int e = blockIdx.x * 256 + t;
    if (e < EE) pose[e] = atomicAdd(&deg[edst[e]], 1);
}

// ---------------- prep: W2 and W1 -> 3 bf16 planes in B-fragment order ----------
// blocks 0..31: W2 (K=256, 16 nt x 8 ks). blocks 32..43: W1 (K pad 79->96,
// 16 nt x 3 ks, rows >=79 zero). B-frag: lane holds B[k=quad*8+j][n=lane&15].

__global__ void k_prep(const void* __restrict__ W2, const void* __restrict__ W1,
                       const int* __restrict__ flag,
                       short8* __restrict__ Bf, short8* __restrict__ Bf1) {
    if (*flag == 0) return;            // bf16-input path: unused
    int bid = blockIdx.x;
    int t = threadIdx.x;
    if (bid < 32) {
        const float* W = (const float*)W2;
        int g = bid * 256 + t;             // 0..8191
        int lane = g & 63;
        int pair = g >> 6;                 // 0..127
        int ks = pair & 7, nt = pair >> 3;
        int quad = lane >> 4, l15 = lane & 15;
        short8 hv, mv, lv;
#pragma unroll
        for (int j = 0; j < 8; ++j) {
            float a = W[(ks * 32 + quad * 8 + j) * HH + nt * 16 + l15];
            unsigned short h, m, l;
            split3(a, h, m, l);
            hv[j] = (short)h; mv[j] = (short)m; lv[j] = (short)l;
        }
        int e = (nt * 8 + ks) * 64 + lane;
        Bf[e]         = hv;
        Bf[e + 8192]  = mv;
        Bf[e + 16384] = lv;
    } else {
        const float* W = (const float*)W1;
        int g = (bid - 32) * 256 + t;      // 0..3071
        int lane = g & 63;
        int pair = g >> 6;                 // 0..47
        int ks = pair % 3, nt = pair / 3;
        int quad = lane >> 4, l15 = lane & 15;
        short8 hv, mv, lv;
#pragma unroll
        for (int j = 0; j < 8; ++j) {
            int k = ks * 32 + quad * 8 + j;
            float a = (k < FIN) ? W[k * HH + nt * 16 + l15] : 0.f;
            unsigned short h, m, l;
            split3(a, h, m, l);
            hv[j] = (short)h; mv[j] = (short)m; lv[j] = (short)l;
        }
        int e = (nt * 3 + ks) * 64 + lane;
        Bf1[e]        = hv;
        Bf1[e + 3072] = mv;
        Bf1[e + 6144] = lv;
    }
}

// ---------------- CSR scan ----------------

__global__ void k_scan_block(const int* __restrict__ deg, int* __restrict__ partial,
                             int* __restrict__ bsums) {
    __shared__ int sm[256];
    int t = threadIdx.x;
    int i = blockIdx.x * 256 + t;
    int v = (i < NN) ? deg[i] : 0;
    sm[t] = v;
    __syncthreads();
    for (int off = 1; off < 256; off <<= 1) {
        int u = (t >= off) ? sm[t - off] : 0;
        __syncthreads();
        sm[t] += u;
        __syncthreads();
    }
    if (i < NN) partial[i] = sm[t];
    if (t == 255) bsums[blockIdx.x] = sm[255];
}

__global__ void k_finalize(const int* __restrict__ deg, const int* __restrict__ partial,
                           const int* __restrict__ bsums, int* __restrict__ offsets,
                           float* __restrict__ dinv) {
    __shared__ int sm[256];
    int b = blockIdx.x;
    int t = threadIdx.x;
    sm[t] = (t < b) ? bsums[t] : 0;
    __syncthreads();
    for (int off = 128; off > 0; off >>= 1) {
        if (t < off) sm[t] += sm[t + off];
        __syncthreads();
    }
    int base = sm[0];
    int i = b * 256 + t;
    if (i >= NN) return;
    int incl = partial[i] + base;
    offsets[i] = incl - deg[i];
    if (i == NN - 1) offsets[NN] = incl;
    dinv[i] = rsqrtf((float)(deg[i] + 1));   // +1 self-loop
}

__global__ void k_fill(const int* __restrict__ esrc, const int* __restrict__ edst,
                       const int* __restrict__ offsets, const int* __restrict__ pose,
                       int* __restrict__ eidx) {
    int e = blockIdx.x * blockDim.x + threadIdx.x;
    if (e < EE) {
        int d = edst[e];
        eidx[offsets[d] + pose[e]] = esrc[e];
    }
}

// ---------------- layer 1 (bf16-input fallback only): full row gather ----------

__global__ __launch_bounds__(256) void k_layer1(
        const int* __restrict__ x, const int* __restrict__ offsets,
        const int* __restrict__ eidx, const float* __restrict__ dinv,
        const void* __restrict__ W1, const void* __restrict__ b1,
        const int* __restrict__ flag, float* __restrict__ h1) {
    if (*flag != 0) return;            // f32 path handled by k_layer1m
    bool f32 = false;
    int node = blockIdx.x * 4 + (threadIdx.x >> 6);
    int lane = threadIdx.x & 63;
    int ch = lane * 4;
    if (node >= NN) return;
    int beg = offsets[node], end = offsets[node + 1];
    float4 acc = make_float4(0.f, 0.f, 0.f, 0.f);
    for (int base = beg; base < end; base += 64) {
        int cnt = min(64, end - base);
        int p  = base + ((lane < cnt) ? lane : 0);
        int sl = eidx[p];
        int xl = x[sl];
        float dvl = dinv[sl];
        for (int q = 0; q < cnt; ++q) {
            int xs   = rli(xl, q);
            float dv = rlf(dvl, q);
            float4 w = ldf4(W1, xs * HH + ch, f32);
            acc.x += dv * w.x; acc.y += dv * w.y; acc.z += dv * w.z; acc.w += dv * w.w;
        }
    }
    float di = dinv[node];
    float d2 = di * di;
    float4 ws = ldf4(W1, x[node] * HH + ch, f32);
    float4 bb = ldf4(b1, ch, f32);
    float4 o;
    o.x = fmaxf(di * acc.x + d2 * ws.x + bb.x, 0.f);
    o.y = fmaxf(di * acc.y + d2 * ws.y + bb.y, 0.f);
    o.z = fmaxf(di * acc.z + d2 * ws.z + bb.z, 0.f);
    o.w = fmaxf(di * acc.w + d2 * ws.w + bb.w, 0.f);
    ((float4*)h1)[(node * HH + ch) >> 2] = o;
}

// ---------------- layer 1 (f32 path): class-coefficient GEMM via bf16x3 MFMA ----
// c[i][f] = di*sum_{x[s]=f} dinv[s] + di^2*[x[i]=f]  (f<79; K padded to 96)
// h1 = relu(c @ W1 + b1). Edge phase reads 12 B/edge of scalars; lane l owns
// c slots l and 64+l (register accumulation, readlane broadcast, deterministic).
// Then 3 k-steps x 6 split products x (2 mt x 4 nt) MFMAs, same map as gemm2.

__global__ __launch_bounds__(256) void k_layer1m(
        const int* __restrict__ x, const int* __restrict__ offsets,
        const int* __restrict__ eidx, const float* __restrict__ dinv,
        const void* __restrict__ b1, const int* __restrict__ flag,
        const short8* __restrict__ Bf1, float* __restrict__ h1) {
    __shared__ __align__(16) unsigned short pl[3 * GR * APAD1];  // 19968 B
    if (*flag == 0) return;            // bf16 path handled by k_layer1
    int t = threadIdx.x;
    int lane = t & 63;
    int rg = t >> 6;
    int b = blockIdx.x;
    int grp = (b < 1560) ? ((b & 7) * 195 + (b >> 3)) : b;
    int r0 = grp * GR;
    unsigned short* pH = pl;
    unsigned short* pM = pl + GR * APAD1;
    unsigned short* pL = pl + 2 * GR * APAD1;

    for (int rr = 0; rr < 8; ++rr) {
        int row = r0 + rg * 8 + rr;
        float c0 = 0.f, c1 = 0.f;
        if (row < NN) {
            float di = dinv[row];
            int beg = offsets[row], end = offsets[row + 1];
            for (int base = beg; base < end; base += 64) {
                int cnt = min(64, end - base);
                int p  = base + ((lane < cnt) ? lane : 0);
                int sl = eidx[p];
                int fl = x[sl];
                float dvl = dinv[sl];
                for (int q = 0; q < cnt; ++q) {
                    int f    = rli(fl, q);
                    float dv = rlf(dvl, q);
                    float val = di * dv;
                    if (lane == f)      c0 += val;
                    if (lane + 64 == f) c1 += val;
                }
            }
            int xi = x[row];
            float d2 = di * di;
            if (lane == xi)      c0 += d2;
            if (lane + 64 == xi) c1 += d2;
        }
        unsigned short h, m, l;
        int base0 = (rg * 8 + rr) * APAD1 + lane;
        split3(c0, h, m, l);
        pH[base0] = h; pM[base0] = m; pL[base0] = l;
        if (lane < 32) {
            split3(c1, h, m, l);
            pH[base0 + 64] = h; pM[base0 + 64] = m; pL[base0 + 64] = l;
        }
    }
    __syncthreads();

    int quad = lane >> 4, l15 = lane & 15;
    int nt0 = rg * 4;
    f32x4 acc[2][4];
#pragma unroll
    for (int mt = 0; mt < 2; ++mt)
#pragma unroll
        for (int nt = 0; nt < 4; ++nt) acc[mt][nt] = (f32x4)0.f;

#pragma unroll
    for (int ks = 0; ks < 3; ++ks) {
        short8 aH[2], aM[2], aL[2];
#pragma unroll
        for (int mt = 0; mt < 2; ++mt) {
            int boff = (mt * 16 + l15) * APAD1 + ks * 32 + quad * 8;
            aH[mt] = *(const short8*)(pH + boff);
            aM[mt] = *(const short8*)(pM + boff);
            aL[mt] = *(const short8*)(pL + boff);
        }
        short8 bH[4], bM[4], bL[4];
#pragma unroll
        for (int nt = 0; nt < 4; ++nt) {
            int e = ((nt0 + nt) * 3 + ks) * 64 + lane;
            bH[nt] = Bf1[e];
            bM[nt] = Bf1[e + 3072];
            bL[nt] = Bf1[e + 6144];
        }
#pragma unroll
        for (int mt = 0; mt < 2; ++mt)
#pragma unroll
            for (int nt = 0; nt < 4; ++nt)
                acc[mt][nt] = __builtin_amdgcn_mfma_f32_16x16x32_bf16(aH[mt], bH[nt], acc[mt][nt], 0, 0, 0);
#pragma unroll
        for (int mt = 0; mt < 2; ++mt)
#pragma unroll
            for (int nt = 0; nt < 4; ++nt)
                acc[mt][nt] = __builtin_amdgcn_mfma_f32_16x16x32_bf16(aM[mt], bH[nt], acc[mt][nt], 0, 0, 0);
#pragma unroll
        for (int mt = 0; mt < 2; ++mt)
#pragma unroll
            for (int nt = 0; nt < 4; ++nt)
                acc[mt][nt] = __builtin_amdgcn_mfma_f32_16x16x32_bf16(aH[mt], bM[nt], acc[mt][nt], 0, 0, 0);
#pragma unroll
        for (int mt = 0; mt < 2; ++mt)
#pragma unroll
            for (int nt = 0; nt < 4; ++nt)
                acc[mt][nt] = __builtin_amdgcn_mfma_f32_16x16x32_bf16(aL[mt], bH[nt], acc[mt][nt], 0, 0, 0);
#pragma unroll
        for (int mt = 0; mt < 2; ++mt)
#pragma unroll
            for (int nt = 0; nt < 4; ++nt)
                acc[mt][nt] = __builtin_amdgcn_mfma_f32_16x16x32_bf16(aH[mt], bL[nt], acc[mt][nt], 0, 0, 0);
#pragma unroll
        for (int mt = 0; mt < 2; ++mt)
#pragma unroll
            for (int nt = 0; nt < 4; ++nt)
                acc[mt][nt] = __builtin_amdgcn_mfma_f32_16x16x32_bf16(aM[mt], bM[nt], acc[mt][nt], 0, 0, 0);
    }

    const float* b1f = (const float*)b1;
    float b1v[4];
#pragma unroll
    for (int nt = 0; nt < 4; ++nt) b1v[nt] = b1f[(nt0 + nt) * 16 + l15];
#pragma unroll
    for (int mt = 0; mt < 2; ++mt) {
#pragma unroll
        for (int r = 0; r < 4; ++r) {
            int row = r0 + mt * 16 + quad * 4 + r;
            if (row < NN) {
#pragma unroll
                for (int nt = 0; nt < 4; ++nt)
                    h1[row * HH + (nt0 + nt) * 16 + l15] =
                        fmaxf(acc[mt][nt][r] + b1v[nt], 0.f);
            }
        }
    }
}

// ---------------- fused agg2 + gemm2: h2 = relu((A_norm @ h1) @ W2 + b2) ----------
// fp32 path: bf16x3-split MFMA (r13) + r14 batched metadata preload.

__global__ __launch_bounds__(256) void k_gemm2(
        const int* __restrict__ offsets, const int* __restrict__ eidx,
        const float* __restrict__ dinv, const float* __restrict__ h1,
        const void* __restrict__ W2, const void* __restrict__ b2,
        const void* __restrict__ Wrel, const void* __restrict__ Wroot,
        const int* __restrict__ flag, const short8* __restrict__ Bf,
        float* __restrict__ Y, float* __restrict__ trel, float* __restrict__ troot) {
    __shared__ __align__(16) char lds[3 * GR * APAD * 2 + 1024];  // 51712 B
    bool f32 = (*flag != 0);
    int t = threadIdx.x;
    int lane = t & 63;
    int rg = t >> 6;
    int b = blockIdx.x;
    int grp = (b < 1560) ? ((b & 7) * 195 + (b >> 3)) : b;
    int r0 = grp * GR;
    int ch = lane * 4;
    const float4* H4 = (const float4*)h1;

    if (f32) {
        unsigned short* pH = (unsigned short*)lds;
        unsigned short* pM = pH + GR * APAD;
        unsigned short* pL = pM + GR * APAD;
        float* redR = (float*)(lds + 3 * GR * APAD * 2);
        float* redO = redR + 128;

        // ---- batched metadata preload for the 8 rows ----
        int begs[8], ends[8];
#pragma unroll
        for (int rr = 0; rr < 8; ++rr) {
            int row = min(r0 + rg * 8 + rr, NN - 1);
            begs[rr] = offsets[row];
            ends[rr] = offsets[row + 1];
        }
        int   sl8[8];
        float dv8[8];
#pragma unroll
        for (int rr = 0; rr < 8; ++rr) {
            int cnt0 = min(64, ends[rr] - begs[rr]);
            int p = begs[rr] + ((lane < cnt0) ? lane : 0);
            p = min(p, EE - 1);
            sl8[rr] = eidx[p];
        }
#pragma unroll
        for (int rr = 0; rr < 8; ++rr) dv8[rr] = dinv[sl8[rr]];

        // ---- stage: gather 8 agg2 rows per wave, split to 3 bf16 planes ----
        for (int rr = 0; rr < 8; ++rr) {
            int row = r0 + rg * 8 + rr;
            float4 acc = make_float4(0.f, 0.f, 0.f, 0.f);
            if (row < NN) {
                int beg = begs[rr], end = ends[rr];
                int sl = sl8[rr];
                float dvl = dv8[rr];
                for (int base = beg; base < end; base += 64) {
                    int cnt = min(64, end - base);
                    if (base != beg) {          // chunks >=2: rare (deg>64)
                        int p = base + ((lane < cnt) ? lane : 0);
                        sl = eidx[p];
                        dvl = dinv[sl];
                    }
                    int q = 0;
                    for (; q + 4 <= cnt; q += 4) {
                        int s0 = rli(sl, q), s1 = rli(sl, q + 1);
                        int s2 = rli(sl, q + 2), s3 = rli(sl, q + 3);
                        float d0 = rlf(dvl, q), d1 = rlf(dvl, q + 1);
                        float d2 = rlf(dvl, q + 2), d3 = rlf(dvl, q + 3);
                        float4 v0 = H4[(s0 * HH + ch) >> 2];
                        float4 v1 = H4[(s1 * HH + ch) >> 2];
                        float4 v2 = H4[(s2 * HH + ch) >> 2];
                        float4 v3 = H4[(s3 * HH + ch) >> 2];
                        acc.x += d0 * v0.x; acc.y += d0 * v0.y; acc.z += d0 * v0.z; acc.w += d0 * v0.w;
                        acc.x += d1 * v1.x; acc.y += d1 * v1.y; acc.z += d1 * v1.z; acc.w += d1 * v1.w;
                        acc.x += d2 * v2.x; acc.y += d2 * v2.y; acc.z += d2 * v2.z; acc.w += d2 * v2.w;
                        acc.x += d3 * v3.x; acc.y += d3 * v3.y; acc.z += d3 * v3.z; acc.w += d3 * v3.w;
                    }
                    for (; q < cnt; ++q) {
                        int s    = rli(sl, q);
                        float dv = rlf(dvl, q);
                        float4 v = H4[(s * HH + ch) >> 2];
                        acc.x += dv * v.x; acc.y += dv * v.y;
                        acc.z += dv * v.z; acc.w += dv * v.w;
                    }
                }
                float di = dinv[row];
                float d2 = di * di;
                float4 v = H4[(row * HH + ch) >> 2];
                acc.x = di * acc.x + d2 * v.x;
                acc.y = di * acc.y + d2 * v.y;
                acc.z = di * acc.z + d2 * v.z;
                acc.w = di * acc.w + d2 * v.w;
            }
            ushort4 hv, mv, lv;
            split3(acc.x, hv.x, mv.x, lv.x);
            split3(acc.y, hv.y, mv.y, lv.y);
            split3(acc.z, hv.z, mv.z, lv.z);
            split3(acc.w, hv.w, mv.w, lv.w);
            int base = (rg * 8 + rr) * APAD + ch;
            *(ushort4*)(pH + base) = hv;
            *(ushort4*)(pM + base) = mv;
            *(ushort4*)(pL + base) = lv;
        }
        __syncthreads();   // cross-wave: A-frag reads span all 32 rows

        // ---- compute: 8 k-steps x (2 mt x 4 nt) tiles x 6 split products ----
        int quad = lane >> 4, l15 = lane & 15;
        int nt0 = rg * 4;
        f32x4 acc[2][4];
#pragma unroll
        for (int mt = 0; mt < 2; ++mt)
#pragma unroll
            for (int nt = 0; nt < 4; ++nt) acc[mt][nt] = (f32x4)0.f;

#pragma unroll
        for (int ks = 0; ks < 8; ++ks) {
            short8 aH[2], aM[2], aL[2];
#pragma unroll
            for (int mt = 0; mt < 2; ++mt) {
                int boff = (mt * 16 + l15) * APAD + ks * 32 + quad * 8;
                aH[mt] = *(const short8*)(pH + boff);
                aM[mt] = *(const short8*)(pM + boff);
                aL[mt] = *(const short8*)(pL + boff);
            }
            short8 bH[4], bM[4], bL[4];
#pragma unroll
            for (int nt = 0; nt < 4; ++nt) {
                int e = ((nt0 + nt) * 8 + ks) * 64 + lane;
                bH[nt] = Bf[e];
                bM[nt] = Bf[e + 8192];
                bL[nt] = Bf[e + 16384];
            }
#pragma unroll
            for (int mt = 0; mt < 2; ++mt)
#pragma unroll
                for (int nt = 0; nt < 4; ++nt)
                    acc[mt][nt] = __builtin_amdgcn_mfma_f32_16x16x32_bf16(aH[mt], bH[nt], acc[mt][nt], 0, 0, 0);
#pragma unroll
            for (int mt = 0; mt < 2; ++mt)
#pragma unroll
                for (int nt = 0; nt < 4; ++nt)
                    acc[mt][nt] = __builtin_amdgcn_mfma_f32_16x16x32_bf16(aM[mt], bH[nt], acc[mt][nt], 0, 0, 0);
#pragma unroll
            for (int mt = 0; mt < 2; ++mt)
#pragma unroll
                for (int nt = 0; nt < 4; ++nt)
                    acc[mt][nt] = __builtin_amdgcn_mfma_f32_16x16x32_bf16(aH[mt], bM[nt], acc[mt][nt], 0, 0, 0);
#pragma unroll
            for (int mt = 0; mt < 2; ++mt)
#pragma unroll
                for (int nt = 0; nt < 4; ++nt)
                    acc[mt][nt] = __builtin_amdgcn_mfma_f32_16x16x32_bf16(aL[mt], bH[nt], acc[mt][nt], 0, 0, 0);
#pragma unroll
            for (int mt = 0; mt < 2; ++mt)
#pragma unroll
                for (int nt = 0; nt < 4; ++nt)
                    acc[mt][nt] = __builtin_amdgcn_mfma_f32_16x16x32_bf16(aH[mt], bL[nt], acc[mt][nt], 0, 0, 0);
#pragma unroll
            for (int mt = 0; mt < 2; ++mt)
#pragma unroll
                for (int nt = 0; nt < 4; ++nt)
                    acc[mt][nt] = __builtin_amdgcn_mfma_f32_16x16x32_bf16(aM[mt], bM[nt], acc[mt][nt], 0, 0, 0);
        }

        // ---- epilogue: relu + store + fused scorer dots ----
        const float* b2f = (const float*)b2;
        const float* wrf = (const float*)Wrel;
        const float* wof = (const float*)Wroot;
        float b2v[4], wrv[4], wov[4];
#pragma unroll
        for (int nt = 0; nt < 4; ++nt) {
            int col = (nt0 + nt) * 16 + l15;
            b2v[nt] = b2f[col]; wrv[nt] = wrf[col]; wov[nt] = wof[col];
        }
#pragma unroll
        for (int mt = 0; mt < 2; ++mt) {
#pragma unroll
            for (int r = 0; r < 4; ++r) {
                int row = r0 + mt * 16 + quad * 4 + r;
                float sr = 0.f, so = 0.f;
#pragma unroll
                for (int nt = 0; nt < 4; ++nt) {
                    float y = fmaxf(acc[mt][nt][r] + b2v[nt], 0.f);
                    if (row < NN) Y[row * HH + (nt0 + nt) * 16 + l15] = y;
                    sr += y * wrv[nt];
                    so += y * wov[nt];
                }
#pragma unroll
                for (int off = 1; off < 16; off <<= 1) {
                    sr += __shfl_xor(sr, off, 64);
                    so += __shfl_xor(so, off, 64);
                }
                if (l15 == 0) {
                    redR[(mt * 16 + quad * 4 + r) * 4 + rg] = sr;
                    redO[(mt * 16 + quad * 4 + r) * 4 + rg] = so;
                }
            }
        }
        __syncthreads();
        if (t < GR) {
            int row = r0 + t;
            if (row < NN) {
                trel[row]  = redR[t * 4] + redR[t * 4 + 1] + redR[t * 4 + 2] + redR[t * 4 + 3];
                troot[row] = redO[t * 4] + redO[t * 4 + 1] + redO[t * 4 + 2] + redO[t * 4 + 3];
            }
        }
        return;
    }

    // ---------------- bf16-input fallback: r12 pk-fma path ----------------
    {
        float (*As)[HH] = (float (*)[HH])lds;
        int c4 = lane;
        for (int rr = 0; rr < 8; ++rr) {
            int row = r0 + rg * 8 + rr;
            float4 acc = make_float4(0.f, 0.f, 0.f, 0.f);
            if (row < NN) {
                int beg = offsets[row], end = offsets[row + 1];
                for (int base = beg; base < end; base += 64) {
                    int cnt = min(64, end - base);
                    int p  = base + ((lane < cnt) ? lane : 0);
                    int sl = eidx[p];
                    float dvl = dinv[sl];
                    for (int q = 0; q < cnt; ++q) {
                        int s    = rli(sl, q);
                        float dv = rlf(dvl, q);
                        float4 v = H4[(s * HH + ch) >> 2];
                        acc.x += dv * v.x; acc.y += dv * v.y;
                        acc.z += dv * v.z; acc.w += dv * v.w;
                    }
                }
                float di = dinv[row];
                float d2 = di * di;
                float4 v = H4[(row * HH + ch) >> 2];
                acc.x = di * acc.x + d2 * v.x;
                acc.y = di * acc.y + d2 * v.y;
                acc.z = di * acc.z + d2 * v.z;
                acc.w = di * acc.w + d2 * v.w;
            }
            *(float4*)&As[rg * 8 + rr][ch] = acc;
        }
        // no barrier: tile slice is wave-private

        v2f accL[8], accH[8];
#pragma unroll
        for (int rr = 0; rr < 8; ++rr) { accL[rr] = (v2f)0.f; accH[rr] = (v2f)0.f; }
        const unsigned short* W = (const unsigned short*)W2;
        ushort4 u0 = *(const ushort4*)&W[0 * HH + c4 * 4];
        ushort4 u1 = *(const ushort4*)&W[1 * HH + c4 * 4];
        ushort4 u2 = *(const ushort4*)&W[2 * HH + c4 * 4];
        ushort4 u3 = *(const ushort4*)&W[3 * HH + c4 * 4];
        for (int k = 0; k < 256; k += 4) {
            ushort4 m0, m1, m2, m3;
            int kn = (k + 4) & 255;
            m0 = *(const ushort4*)&W[(kn + 0) * HH + c4 * 4];
            m1 = *(const ushort4*)&W[(kn + 1) * HH + c4 * 4];
            m2 = *(const ushort4*)&W[(kn + 2) * HH + c4 * 4];
            m3 = *(const ushort4*)&W[(kn + 3) * HH + c4 * 4];
            v2f w0L = {bfbits(u0.x), bfbits(u0.y)}, w0H = {bfbits(u0.z), bfbits(u0.w)};
            v2f w1L = {bfbits(u1.x), bfbits(u1.y)}, w1H = {bfbits(u1.z), bfbits(u1.w)};
            v2f w2L = {bfbits(u2.x), bfbits(u2.y)}, w2H = {bfbits(u2.z), bfbits(u2.w)};
            v2f w3L = {bfbits(u3.x), bfbits(u3.y)}, w3H = {bfbits(u3.z), bfbits(u3.w)};
#pragma unroll
            for (int rr = 0; rr < 8; ++rr) {
                float4 a = *(const float4*)&As[rg * 8 + rr][k];
                v2f ax = a.x, ay = a.y, az = a.z, aw = a.w;
                accL[rr] += ax * w0L; accH[rr] += ax * w0H;
                accL[rr] += ay * w1L; accH[rr] += ay * w1H;
                accL[rr] += az * w2L; accH[rr] += az * w2H;
                accL[rr] += aw * w3L; accH[rr] += aw * w3H;
            }
            u0 = m0; u1 = m1; u2 = m2; u3 = m3;
        }
        float4 bb = ldf4(b2, c4 * 4, f32);
        float4 wr = ldf4(Wrel, c4 * 4, f32);
        float4 wo = ldf4(Wroot, c4 * 4, f32);
#pragma unroll
        for (int rr = 0; rr < 8; ++rr) {
            int row = r0 + rg * 8 + rr;
            float4 y;
            y.x = fmaxf(accL[rr].x + bb.x, 0.f);
            y.y = fmaxf(accL[rr].y + bb.y, 0.f);
            y.z = fmaxf(accH[rr].x + bb.z, 0.f);
            y.w = fmaxf(accH[rr].y + bb.w, 0.f);
            if (row < NN)
                *(float4*)&Y[row * HH + c4 * 4] = y;
            float sr = y.x * wr.x + y.y * wr.y + y.z * wr.z + y.w * wr.w;
            float so = y.x * wo.x + y.y * wo.y + y.z * wo.z + y.w * wo.w;
#pragma unroll
            for (int off = 32; off > 0; off >>= 1) {
                sr += __shfl_xor(sr, off, 64);
                so += __shfl_xor(so, off, 64);
            }
            if (c4 == 0 && row < NN) { trel[row] = sr; troot[row] = so; }
        }
    }
}

// ---------------- score -> per-graph top-k (selection only) ----------------

__global__ __launch_bounds__(1024) void k_topk(
        const int* __restrict__ offsets, const int* __restrict__ eidx,
        const float* __restrict__ trel, const float* __restrict__ troot,
        const void* __restrict__ brel, const int* __restrict__ flag,
        int* __restrict__ snode, float* __restrict__ sw) {
    __shared__ float s[1024];
    __shared__ int   id[1024];
    bool f32 = (*flag != 0);
    int b = blockIdx.x, t = threadIdx.x;
    float br = ldf(brel, 0, f32);
    if (t < NPGc) {
        int node = b * NPGc + t;
        float sc = br + troot[node];
        int beg = offsets[node], end = offsets[node + 1];
        for (int p = beg; p < end; ++p) sc += trel[eidx[p]];
        s[t] = sc; id[t] = t;
    } else { s[t] = -FLT_MAX; id[t] = 0x7FFFFFFF; }
    for (int k = 2; k <= 1024; k <<= 1) {
        for (int j = k >> 1; j > 0; j >>= 1) {
            __syncthreads();
            int l = t ^ j;
            if (l > t) {
                float si = s[t], sl = s[l];
                int   ii = id[t], il = id[l];
                bool iFirst = (si > sl) || (si == sl && ii < il);
                bool doSwap = ((t & k) == 0) ? (!iFirst) : iFirst;
                if (doSwap) { s[t] = sl; s[l] = si; id[t] = il; id[l] = ii; }
            }
        }
    }
    __syncthreads();
    if (t < KK) {
        snode[b * KK + t] = b * NPGc + id[t];
        sw[b * KK + t]    = tanhf(s[t]);
    }
}

// ---------------- pool: partial max over 63-row slices, 8 blocks/graph ----------

__global__ __launch_bounds__(256) void k_pool(
        const int* __restrict__ snode, const float* __restrict__ sw,
        const float* __restrict__ h2, float* __restrict__ part) {
    __shared__ int   sn[64];
    __shared__ float sv[64];
    int b = blockIdx.x >> 3;
    int j = blockIdx.x & 7;
    int t = threadIdx.x;
    int q0 = j * 63;
    int cnt = min(63, KK - q0);
    if (t < cnt) {
        sn[t] = snode[b * KK + q0 + t];
        sv[t] = sw[b * KK + q0 + t];
    }
    __syncthreads();
    float m = -FLT_MAX;
    for (int q = 0; q < cnt; ++q)
        m = fmaxf(m, h2[sn[q] * HH + t] * sv[q]);
    part[blockIdx.x * 256 + t] = m;
}

__global__ __launch_bounds__(256) void k_out(
        const float* __restrict__ part, const int* __restrict__ flag,
        void* __restrict__ out) {
    int b = blockIdx.x, t = threadIdx.x;
    float r = part[(b * 8 + 0) * 256 + t];
#pragma unroll
    for (int j = 1; j < 8; ++j)
        r = fmaxf(r, part[(b * 8 + j) * 256 + t]);
    if (*flag) ((float*)out)[b * HH + t] = r;
    else       ((bf16*)out)[b * HH + t] = __float2bfloat16(r);
}

// ---------------- launch ----------------

extern "C" void kernel_launch(void* const* d_in, const int* in_sizes, int n_in,
                              void* d_out, int out_size, void* d_ws, size_t ws_size,
                              hipStream_t stream) {
    const int*  x    = (const int*)d_in[0];
    const int*  esrc = (const int*)d_in[1];
    const int*  edst = esrc + EE;
    const void* W1   = d_in[3];
    const void* b1   = d_in[4];
    const void* W2   = d_in[5];
    const void* b2   = d_in[6];
    const void* Wrel = d_in[7];
    const void* brel = d_in[8];
    const void* Wroot= d_in[9];

    char* w = (char*)d_ws;
    size_t off = 0;
    auto carve = [&](size_t bytes) -> void* {
        void* p = w + off;
        off = (off + bytes + 255) & ~(size_t)255;
        return p;
    };
    int*    flag    = (int*)   carve(256);
    int*    deg     = (int*)   carve((size_t)NN * 4);
    int*    partial = (int*)   carve((size_t)NN * 4);
    int*    bsums   = (int*)   carve(256 * 4);
    int*    offsets = (int*)   carve((size_t)(NN + 1) * 4);
    int*    eidx    = (int*)   carve((size_t)EE * 4);
    int*    pose    = (int*)   carve((size_t)EE * 4);
    float*  dinv    = (float*) carve((size_t)NN * 4);
    float*  trel    = (float*) carve((size_t)NN * 4);
    float*  troot   = (float*) carve((size_t)NN * 4);
    int*    snode   = (int*)   carve((size_t)BB * KK * 4);
    float*  swb     = (float*) carve((size_t)BB * KK * 4);
    float*  part    = (float*) carve((size_t)BB * 8 * 256 * 4);
    short8* Bf      = (short8*)carve((size_t)3 * 8192 * 16);  // W2 bf16x3 B-frags
    short8* Bf1     = (short8*)carve((size_t)3 * 3072 * 16);  // W1 bf16x3 B-frags
    float*  bufA    = (float*) carve((size_t)NN * HH * 4);    // h1
    float*  bufB    = (float*) carve((size_t)NN * HH * 4);    // h2
    (void)ws_size; (void)in_sizes; (void)n_in; (void)out_size;

    const int NB   = (NN + 255) / 256;     // 196
    const int EBLK = (EE + 255) / 256;     // 1172
    const int NGB  = (NN + 3) / 4;         // 12500
    const int GB   = (NN + GR - 1) / GR;   // 1563

    hipMemsetAsync(deg, 0, (size_t)NN * 4, stream);
    k_count     <<<EBLK + 1, 256, 0, stream>>>(edst, deg, pose,
                                               (const unsigned int*)W1, flag);
    k_prep      <<<44, 256, 0, stream>>>(W2, W1, flag, Bf, Bf1);
    k_scan_block<<<NB, 256, 0, stream>>>(deg, partial, bsums);
    k_finalize  <<<NB, 256, 0, stream>>>(deg, partial, bsums, offsets, dinv);
    k_fill      <<<EBLK, 256, 0, stream>>>(esrc, edst, offsets, pose, eidx);

    k_layer1    <<<NGB, 256, 0, stream>>>(x, offsets, eidx, dinv, W1, b1, flag, bufA);
    k_layer1m   <<<GB, 256, 0, stream>>>(x, offsets, eidx, dinv, b1, flag, Bf1, bufA);
    k_gemm2     <<<GB, 256, 0, stream>>>(offsets, eidx, dinv, bufA,
                                         W2, b2, Wrel, Wroot, flag,
                                         Bf, bufB, trel, troot);
    k_topk      <<<BB, 1024, 0, stream>>>(offsets, eidx, trel, troot, brel, flag,
                                          snode, swb);
    k_pool      <<<BB * 8, 256, 0, stream>>>(snode, swb, bufB, part);
    k_out       <<<BB, 256, 0, stream>>>(part, flag, d_out);
}

// Round 16
// 242.690 us; speedup vs baseline: 1.0228x; 1.0228x over previous
//
#include <hip/hip_runtime.h>
#include <hip/hip_bf16.h>
#include <float.h>
#include <math.h>

#define NN   50000
#define BB   50
#define NPGc 1000
#define EE   300000
#define HH   256
#define FIN  79
#define KK   500
#define GR   32      // gemm rows per block
#define APAD 264     // gemm2 A-plane LDS row stride in ushorts (256 + 8 pad)

typedef __hip_bfloat16 bf16;
typedef float v2f __attribute__((ext_vector_type(2)));
typedef short short8 __attribute__((ext_vector_type(8)));
typedef float f32x4 __attribute__((ext_vector_type(4)));

__device__ __forceinline__ float bfbits(unsigned short h) {
    return __uint_as_float(((unsigned int)h) << 16);
}
__device__ __forceinline__ float ldf(const void* p, int i, bool f32) {
    return f32 ? ((const float*)p)[i] : bfbits(((const unsigned short*)p)[i]);
}
__device__ __forceinline__ float4 ldf4(const void* p, int i, bool f32) {
    if (f32) return ((const float4*)p)[i >> 2];
    ushort4 u = ((const ushort4*)p)[i >> 2];
    return make_float4(bfbits(u.x), bfbits(u.y), bfbits(u.z), bfbits(u.w));
}
__device__ __forceinline__ int   rli(int v, int q) {
    return __builtin_amdgcn_readlane(v, q);
}
__device__ __forceinline__ float rlf(float v, int q) {
    return __int_as_float(__builtin_amdgcn_readlane(__float_as_int(v), q));
}
// fp32 -> 3 bf16 planes (RNE at each step; residuals exact) ~2^-24 total error
__device__ __forceinline__ void split3(float a, unsigned short& h,
                                       unsigned short& m, unsigned short& l) {
    unsigned int u = __float_as_uint(a);
    h = (unsigned short)((u + 0x7FFFu + ((u >> 16) & 1u)) >> 16);
    float r1 = a - bfbits(h);
    u = __float_as_uint(r1);
    m = (unsigned short)((u + 0x7FFFu + ((u >> 16) & 1u)) >> 16);
    float r2 = r1 - bfbits(m);
    u = __float_as_uint(r2);
    l = (unsigned short)((u + 0x7FFFu + ((u >> 16) & 1u)) >> 16);
}

// ---------------- count (+ dtype detect in the extra block) ----------------
// Also records each edge's intra-bucket position so k_fill needs no atomics.

__global__ void k_count(const int* __restrict__ edst, int* __restrict__ deg,
                        int* __restrict__ pose,
                        const unsigned int* __restrict__ w1, int* __restrict__ flag) {
    int t = threadIdx.x;
    if (blockIdx.x == gridDim.x - 1) {
        __shared__ int sm[256];
        int c = 0;
        for (int i = t; i < 10112; i += 256) {
            unsigned int e = (w1[i] >> 7) & 0xFFu;
            c += (e >= 128u) ? 1 : 0;
        }
        sm[t] = c;
        __syncthreads();
        for (int off = 128; off > 0; off >>= 1) {
            if (t < off) sm[t] += sm[t + off];
            __syncthreads();
        }
        if (t == 0) flag[0] = (sm[0] > 500) ? 1 : 0;
        return;
    }
    int e = blockIdx.x * 256 + t;
    if (e < EE) pose[e] = atomicAdd(&deg[edst[e]], 1);
}

// ---------------- prep: W2 -> 3 bf16 planes in B-fragment order ----------------

__global__ void k_prep(const void* __restrict__ W2, const int* __restrict__ flag,
                       short8* __restrict__ Bf) {
    if (*flag == 0) return;            // bf16-input path: unused
    const float* W = (const float*)W2;
    int g = blockIdx.x * 256 + threadIdx.x;   // 0..8191
    int lane = g & 63;
    int pair = g >> 6;                 // 0..127
    int ks = pair & 7, nt = pair >> 3;
    int quad = lane >> 4, l15 = lane & 15;
    short8 hv, mv, lv;
#pragma unroll
    for (int j = 0; j < 8; ++j) {
        float a = W[(ks * 32 + quad * 8 + j) * HH + nt * 16 + l15];
        unsigned short h, m, l;
        split3(a, h, m, l);
        hv[j] = (short)h; mv[j] = (short)m; lv[j] = (short)l;
    }
    int e = (nt * 8 + ks) * 64 + lane;
    Bf[e]         = hv;
    Bf[e + 8192]  = mv;
    Bf[e + 16384] = lv;
}

// ---------------- CSR scan ----------------

__global__ void k_scan_block(const int* __restrict__ deg, int* __restrict__ partial,
                             int* __restrict__ bsums) {
    __shared__ int sm[256];
    int t = threadIdx.x;
    int i = blockIdx.x * 256 + t;
    int v = (i < NN) ? deg[i] : 0;
    sm[t] = v;
    __syncthreads();
    for (int off = 1; off < 256; off <<= 1) {
        int u = (t >= off) ? sm[t - off] : 0;
        __syncthreads();
        sm[t] += u;
        __syncthreads();
    }
    if (i < NN) partial[i] = sm[t];
    if (t == 255) bsums[blockIdx.x] = sm[255];
}

__global__ void k_finalize(const int* __restrict__ deg, const int* __restrict__ partial,
                           const int* __restrict__ bsums, int* __restrict__ offsets,
                           float* __restrict__ dinv) {
    __shared__ int sm[256];
    int b = blockIdx.x;
    int t = threadIdx.x;
    sm[t] = (t < b) ? bsums[t] : 0;
    __syncthreads();
    for (int off = 128; off > 0; off >>= 1) {
        if (t < off) sm[t] += sm[t + off];
        __syncthreads();
    }
    int base = sm[0];
    int i = b * 256 + t;
    if (i >= NN) return;
    int incl = partial[i] + base;
    offsets[i] = incl - deg[i];
    if (i == NN - 1) offsets[NN] = incl;
    dinv[i] = rsqrtf((float)(deg[i] + 1));   // +1 self-loop
}

__global__ void k_fill(const int* __restrict__ esrc, const int* __restrict__ edst,
                       const int* __restrict__ offsets, const int* __restrict__ pose,
                       int* __restrict__ eidx) {
    int e = blockIdx.x * blockDim.x + threadIdx.x;
    if (e < EE) {
        int d = edst[e];
        eidx[offsets[d] + pose[e]] = esrc[e];
    }
}

// ---------------- layer 1: h1 = relu(GCN(one_hot(x), W1, b1)) ----------------
// Wave-per-node; readlane broadcast; ZERO-PADDED 4-wide load pipeline (r16):
// remainder edges are folded into a final 4-wide group with weight 0 (exact),
// so every row's row-loads issue in fully pipelined groups of 4.

__global__ __launch_bounds__(256) void k_layer1(
        const int* __restrict__ x, const int* __restrict__ offsets,
        const int* __restrict__ eidx, const float* __restrict__ dinv,
        const void* __restrict__ W1, const void* __restrict__ b1,
        const int* __restrict__ flag, float* __restrict__ h1) {
    bool f32 = (*flag != 0);
    int node = blockIdx.x * 4 + (threadIdx.x >> 6);
    int lane = threadIdx.x & 63;
    int ch = lane * 4;
    if (node >= NN) return;
    int beg = offsets[node], end = offsets[node + 1];
    float4 acc = make_float4(0.f, 0.f, 0.f, 0.f);
    for (int base = beg; base < end; base += 64) {
        int cnt = min(64, end - base);
        int p  = base + ((lane < cnt) ? lane : 0);
        int sl = eidx[p];
        int xl = x[sl];
        float dvl = dinv[sl];
        for (int q = 0; q < cnt; q += 4) {
            int i1 = min(q + 1, cnt - 1), i2 = min(q + 2, cnt - 1), i3 = min(q + 3, cnt - 1);
            int x0 = rli(xl, q),  x1 = rli(xl, i1);
            int x2 = rli(xl, i2), x3 = rli(xl, i3);
            float d0 = rlf(dvl, q);
            float d1 = (q + 1 < cnt) ? rlf(dvl, i1) : 0.f;
            float d2 = (q + 2 < cnt) ? rlf(dvl, i2) : 0.f;
            float d3 = (q + 3 < cnt) ? rlf(dvl, i3) : 0.f;
            float4 w0 = ldf4(W1, x0 * HH + ch, f32);
            float4 w1 = ldf4(W1, x1 * HH + ch, f32);
            float4 w2 = ldf4(W1, x2 * HH + ch, f32);
            float4 w3 = ldf4(W1, x3 * HH + ch, f32);
            acc.x += d0 * w0.x; acc.y += d0 * w0.y; acc.z += d0 * w0.z; acc.w += d0 * w0.w;
            acc.x += d1 * w1.x; acc.y += d1 * w1.y; acc.z += d1 * w1.z; acc.w += d1 * w1.w;
            acc.x += d2 * w2.x; acc.y += d2 * w2.y; acc.z += d2 * w2.z; acc.w += d2 * w2.w;
            acc.x += d3 * w3.x; acc.y += d3 * w3.y; acc.z += d3 * w3.z; acc.w += d3 * w3.w;
        }
    }
    float di = dinv[node];
    float d2 = di * di;
    float4 ws = ldf4(W1, x[node] * HH + ch, f32);
    float4 bb = ldf4(b1, ch, f32);
    float4 o;
    o.x = fmaxf(di * acc.x + d2 * ws.x + bb.x, 0.f);
    o.y = fmaxf(di * acc.y + d2 * ws.y + bb.y, 0.f);
    o.z = fmaxf(di * acc.z + d2 * ws.z + bb.z, 0.f);
    o.w = fmaxf(di * acc.w + d2 * ws.w + bb.w, 0.f);
    ((float4*)h1)[(node * HH + ch) >> 2] = o;
}

// ---------------- fused agg2 + gemm2: h2 = relu((A_norm @ h1) @ W2 + b2) ----------
// fp32 path: bf16x3-split MFMA (r13) + r14 batched metadata preload + r16
// zero-padded 4-wide gather pipeline (no serial remainder; exact).

__global__ __launch_bounds__(256) void k_gemm2(
        const int* __restrict__ offsets, const int* __restrict__ eidx,
        const float* __restrict__ dinv, const float* __restrict__ h1,
        const void* __restrict__ W2, const void* __restrict__ b2,
        const void* __restrict__ Wrel, const void* __restrict__ Wroot,
        const int* __restrict__ flag, const short8* __restrict__ Bf,
        float* __restrict__ Y, float* __restrict__ trel, float* __restrict__ troot) {
    __shared__ __align__(16) char lds[3 * GR * APAD * 2 + 1024];  // 51712 B
    bool f32 = (*flag != 0);
    int t = threadIdx.x;
    int lane = t & 63;
    int rg = t >> 6;
    int b = blockIdx.x;
    int grp = (b < 1560) ? ((b & 7) * 195 + (b >> 3)) : b;
    int r0 = grp * GR;
    int ch = lane * 4;
    const float4* H4 = (const float4*)h1;

    if (f32) {
        unsigned short* pH = (unsigned short*)lds;
        unsigned short* pM = pH + GR * APAD;
        unsigned short* pL = pM + GR * APAD;
        float* redR = (float*)(lds + 3 * GR * APAD * 2);
        float* redO = redR + 128;

        // ---- batched metadata preload for the 8 rows ----
        int begs[8], ends[8];
#pragma unroll
        for (int rr = 0; rr < 8; ++rr) {
            int row = min(r0 + rg * 8 + rr, NN - 1);
            begs[rr] = offsets[row];
            ends[rr] = offsets[row + 1];
        }
        int   sl8[8];
        float dv8[8];
#pragma unroll
        for (int rr = 0; rr < 8; ++rr) {
            int cnt0 = min(64, ends[rr] - begs[rr]);
            int p = begs[rr] + ((lane < cnt0) ? lane : 0);
            p = min(p, EE - 1);
            sl8[rr] = eidx[p];
        }
#pragma unroll
        for (int rr = 0; rr < 8; ++rr) dv8[rr] = dinv[sl8[rr]];

        // ---- stage: gather 8 agg2 rows per wave, split to 3 bf16 planes ----
        for (int rr = 0; rr < 8; ++rr) {
            int row = r0 + rg * 8 + rr;
            float4 acc = make_float4(0.f, 0.f, 0.f, 0.f);
            if (row < NN) {
                int beg = begs[rr], end = ends[rr];
                int sl = sl8[rr];
                float dvl = dv8[rr];
                for (int base = beg; base < end; base += 64) {
                    int cnt = min(64, end - base);
                    if (base != beg) {          // chunks >=2: rare (deg>64)
                        int p = base + ((lane < cnt) ? lane : 0);
                        sl = eidx[p];
                        dvl = dinv[sl];
                    }
                    for (int q = 0; q < cnt; q += 4) {
                        int i1 = min(q + 1, cnt - 1), i2 = min(q + 2, cnt - 1), i3 = min(q + 3, cnt - 1);
                        int s0 = rli(sl, q),  s1 = rli(sl, i1);
                        int s2 = rli(sl, i2), s3 = rli(sl, i3);
                        float d0 = rlf(dvl, q);
                        float d1 = (q + 1 < cnt) ? rlf(dvl, i1) : 0.f;
                        float d2 = (q + 2 < cnt) ? rlf(dvl, i2) : 0.f;
                        float d3 = (q + 3 < cnt) ? rlf(dvl, i3) : 0.f;
                        float4 v0 = H4[(s0 * HH + ch) >> 2];
                        float4 v1 = H4[(s1 * HH + ch) >> 2];
                        float4 v2 = H4[(s2 * HH + ch) >> 2];
                        float4 v3 = H4[(s3 * HH + ch) >> 2];
                        acc.x += d0 * v0.x; acc.y += d0 * v0.y; acc.z += d0 * v0.z; acc.w += d0 * v0.w;
                        acc.x += d1 * v1.x; acc.y += d1 * v1.y; acc.z += d1 * v1.z; acc.w += d1 * v1.w;
                        acc.x += d2 * v2.x; acc.y += d2 * v2.y; acc.z += d2 * v2.z; acc.w += d2 * v2.w;
                        acc.x += d3 * v3.x; acc.y += d3 * v3.y; acc.z += d3 * v3.z; acc.w += d3 * v3.w;
                    }
                }
                float di = dinv[row];
                float d2 = di * di;
                float4 v = H4[(row * HH + ch) >> 2];
                acc.x = di * acc.x + d2 * v.x;
                acc.y = di * acc.y + d2 * v.y;
                acc.z = di * acc.z + d2 * v.z;
                acc.w = di * acc.w + d2 * v.w;
            }
            ushort4 hv, mv, lv;
            split3(acc.x, hv.x, mv.x, lv.x);
            split3(acc.y, hv.y, mv.y, lv.y);
            split3(acc.z, hv.z, mv.z, lv.z);
            split3(acc.w, hv.w, mv.w, lv.w);
            int base = (rg * 8 + rr) * APAD + ch;
            *(ushort4*)(pH + base) = hv;
            *(ushort4*)(pM + base) = mv;
            *(ushort4*)(pL + base) = lv;
        }
        __syncthreads();   // cross-wave: A-frag reads span all 32 rows

        // ---- compute: 8 k-steps x (2 mt x 4 nt) tiles x 6 split products ----
        int quad = lane >> 4, l15 = lane & 15;
        int nt0 = rg * 4;
        f32x4 acc[2][4];
#pragma unroll
        for (int mt = 0; mt < 2; ++mt)
#pragma unroll
            for (int nt = 0; nt < 4; ++nt) acc[mt][nt] = (f32x4)0.f;

#pragma unroll
        for (int ks = 0; ks < 8; ++ks) {
            short8 aH[2], aM[2], aL[2];
#pragma unroll
            for (int mt = 0; mt < 2; ++mt) {
                int boff = (mt * 16 + l15) * APAD + ks * 32 + quad * 8;
                aH[mt] = *(const short8*)(pH + boff);
                aM[mt] = *(const short8*)(pM + boff);
                aL[mt] = *(const short8*)(pL + boff);
            }
            short8 bH[4], bM[4], bL[4];
#pragma unroll
            for (int nt = 0; nt < 4; ++nt) {
                int e = ((nt0 + nt) * 8 + ks) * 64 + lane;
                bH[nt] = Bf[e];
                bM[nt] = Bf[e + 8192];
                bL[nt] = Bf[e + 16384];
            }
#pragma unroll
            for (int mt = 0; mt < 2; ++mt)
#pragma unroll
                for (int nt = 0; nt < 4; ++nt)
                    acc[mt][nt] = __builtin_amdgcn_mfma_f32_16x16x32_bf16(aH[mt], bH[nt], acc[mt][nt], 0, 0, 0);
#pragma unroll
            for (int mt = 0; mt < 2; ++mt)
#pragma unroll
                for (int nt = 0; nt < 4; ++nt)
                    acc[mt][nt] = __builtin_amdgcn_mfma_f32_16x16x32_bf16(aM[mt], bH[nt], acc[mt][nt], 0, 0, 0);
#pragma unroll
            for (int mt = 0; mt < 2; ++mt)
#pragma unroll
                for (int nt = 0; nt < 4; ++nt)
                    acc[mt][nt] = __builtin_amdgcn_mfma_f32_16x16x32_bf16(aH[mt], bM[nt], acc[mt][nt], 0, 0, 0);
#pragma unroll
            for (int mt = 0; mt < 2; ++mt)
#pragma unroll
                for (int nt = 0; nt < 4; ++nt)
                    acc[mt][nt] = __builtin_amdgcn_mfma_f32_16x16x32_bf16(aL[mt], bH[nt], acc[mt][nt], 0, 0, 0);
#pragma unroll
            for (int mt = 0; mt < 2; ++mt)
#pragma unroll
                for (int nt = 0; nt < 4; ++nt)
                    acc[mt][nt] = __builtin_amdgcn_mfma_f32_16x16x32_bf16(aH[mt], bL[nt], acc[mt][nt], 0, 0, 0);
#pragma unroll
            for (int mt = 0; mt < 2; ++mt)
#pragma unroll
                for (int nt = 0; nt < 4; ++nt)
                    acc[mt][nt] = __builtin_amdgcn_mfma_f32_16x16x32_bf16(aM[mt], bM[nt], acc[mt][nt], 0, 0, 0);
        }

        // ---- epilogue: relu + store + fused scorer dots ----
        const float* b2f = (const float*)b2;
        const float* wrf = (const float*)Wrel;
        const float* wof = (const float*)Wroot;
        float b2v[4], wrv[4], wov[4];
#pragma unroll
        for (int nt = 0; nt < 4; ++nt) {
            int col = (nt0 + nt) * 16 + l15;
            b2v[nt] = b2f[col]; wrv[nt] = wrf[col]; wov[nt] = wof[col];
        }
#pragma unroll
        for (int mt = 0; mt < 2; ++mt) {
#pragma unroll
            for (int r = 0; r < 4; ++r) {
                int row = r0 + mt * 16 + quad * 4 + r;
                float sr = 0.f, so = 0.f;
#pragma unroll
                for (int nt = 0; nt < 4; ++nt) {
                    float y = fmaxf(acc[mt][nt][r] + b2v[nt], 0.f);
                    if (row < NN) Y[row * HH + (nt0 + nt) * 16 + l15] = y;
                    sr += y * wrv[nt];
                    so += y * wov[nt];
                }
#pragma unroll
                for (int off = 1; off < 16; off <<= 1) {
                    sr += __shfl_xor(sr, off, 64);
                    so += __shfl_xor(so, off, 64);
                }
                if (l15 == 0) {
                    redR[(mt * 16 + quad * 4 + r) * 4 + rg] = sr;
                    redO[(mt * 16 + quad * 4 + r) * 4 + rg] = so;
                }
            }
        }
        __syncthreads();
        if (t < GR) {
            int row = r0 + t;
            if (row < NN) {
                trel[row]  = redR[t * 4] + redR[t * 4 + 1] + redR[t * 4 + 2] + redR[t * 4 + 3];
                troot[row] = redO[t * 4] + redO[t * 4 + 1] + redO[t * 4 + 2] + redO[t * 4 + 3];
            }
        }
        return;
    }

    // ---------------- bf16-input fallback: r12 pk-fma path ----------------
    {
        float (*As)[HH] = (float (*)[HH])lds;
        int c4 = lane;
        for (int rr = 0; rr < 8; ++rr) {
            int row = r0 + rg * 8 + rr;
            float4 acc = make_float4(0.f, 0.f, 0.f, 0.f);
            if (row < NN) {
                int beg = offsets[row], end = offsets[row + 1];
                for (int base = beg; base < end; base += 64) {
                    int cnt = min(64, end - base);
                    int p  = base + ((lane < cnt) ? lane : 0);
                    int sl = eidx[p];
                    float dvl = dinv[sl];
                    for (int q = 0; q < cnt; ++q) {
                        int s    = rli(sl, q);
                        float dv = rlf(dvl, q);
                        float4 v = H4[(s * HH + ch) >> 2];
                        acc.x += dv * v.x; acc.y += dv * v.y;
                        acc.z += dv * v.z; acc.w += dv * v.w;
                    }
                }
                float di = dinv[row];
                float d2 = di * di;
                float4 v = H4[(row * HH + ch) >> 2];
                acc.x = di * acc.x + d2 * v.x;
                acc.y = di * acc.y + d2 * v.y;
                acc.z = di * acc.z + d2 * v.z;
                acc.w = di * acc.w + d2 * v.w;
            }
            *(float4*)&As[rg * 8 + rr][ch] = acc;
        }
        // no barrier: tile slice is wave-private

        v2f accL[8], accH[8];
#pragma unroll
        for (int rr = 0; rr < 8; ++rr) { accL[rr] = (v2f)0.f; accH[rr] = (v2f)0.f; }
        const unsigned short* W = (const unsigned short*)W2;
        ushort4 u0 = *(const ushort4*)&W[0 * HH + c4 * 4];
        ushort4 u1 = *(const ushort4*)&W[1 * HH + c4 * 4];
        ushort4 u2 = *(const ushort4*)&W[2 * HH + c4 * 4];
        ushort4 u3 = *(const ushort4*)&W[3 * HH + c4 * 4];
        for (int k = 0; k < 256; k += 4) {
            ushort4 m0, m1, m2, m3;
            int kn = (k + 4) & 255;
            m0 = *(const ushort4*)&W[(kn + 0) * HH + c4 * 4];
            m1 = *(const ushort4*)&W[(kn + 1) * HH + c4 * 4];
            m2 = *(const ushort4*)&W[(kn + 2) * HH + c4 * 4];
            m3 = *(const ushort4*)&W[(kn + 3) * HH + c4 * 4];
            v2f w0L = {bfbits(u0.x), bfbits(u0.y)}, w0H = {bfbits(u0.z), bfbits(u0.w)};
            v2f w1L = {bfbits(u1.x), bfbits(u1.y)}, w1H = {bfbits(u1.z), bfbits(u1.w)};
            v2f w2L = {bfbits(u2.x), bfbits(u2.y)}, w2H = {bfbits(u2.z), bfbits(u2.w)};
            v2f w3L = {bfbits(u3.x), bfbits(u3.y)}, w3H = {bfbits(u3.z), bfbits(u3.w)};
#pragma unroll
            for (int rr = 0; rr < 8; ++rr) {
                float4 a = *(const float4*)&As[rg * 8 + rr][k];
                v2f ax = a.x, ay = a.y, az = a.z, aw = a.w;
                accL[rr] += ax * w0L; accH[rr] += ax * w0H;
                accL[rr] += ay * w1L; accH[rr] += ay * w1H;
                accL[rr] += az * w2L; accH[rr] += az * w2H;
                accL[rr] += aw * w3L; accH[rr] += aw * w3H;
            }
            u0 = m0; u1 = m1; u2 = m2; u3 = m3;
        }
        float4 bb = ldf4(b2, c4 * 4, f32);
        float4 wr = ldf4(Wrel, c4 * 4, f32);
        float4 wo = ldf4(Wroot, c4 * 4, f32);
#pragma unroll
        for (int rr = 0; rr < 8; ++rr) {
            int row = r0 + rg * 8 + rr;
            float4 y;
            y.x = fmaxf(accL[rr].x + bb.x, 0.f);
            y.y = fmaxf(accL[rr].y + bb.y, 0.f);
            y.z = fmaxf(accH[rr].x + bb.z, 0.f);
            y.w = fmaxf(accH[rr].y + bb.w, 0.f);
            if (row < NN)
                *(float4*)&Y[row * HH + c4 * 4] = y;
            float sr = y.x * wr.x + y.y * wr.y + y.z * wr.z + y.w * wr.w;
            float so = y.x * wo.x + y.y * wo.y + y.z * wo.z + y.w * wo.w;
#pragma unroll
            for (int off = 32; off > 0; off >>= 1) {
                sr += __shfl_xor(sr, off, 64);
                so += __shfl_xor(so, off, 64);
            }
            if (c4 == 0 && row < NN) { trel[row] = sr; troot[row] = so; }
        }
    }
}

// ---------------- score -> per-graph top-k (selection only) ----------------

__global__ __launch_bounds__(1024) void k_topk(
        const int* __restrict__ offsets, const int* __restrict__ eidx,
        const float* __restrict__ trel, const float* __restrict__ troot,
        const void* __restrict__ brel, const int* __restrict__ flag,
        int* __restrict__ snode, float* __restrict__ sw) {
    __shared__ float s[1024];
    __shared__ int   id[1024];
    bool f32 = (*flag != 0);
    int b = blockIdx.x, t = threadIdx.x;
    float br = ldf(brel, 0, f32);
    if (t < NPGc) {
        int node = b * NPGc + t;
        float sc = br + troot[node];
        int beg = offsets[node], end = offsets[node + 1];
        for (int p = beg; p < end; ++p) sc += trel[eidx[p]];
        s[t] = sc; id[t] = t;
    } else { s[t] = -FLT_MAX; id[t] = 0x7FFFFFFF; }
    for (int k = 2; k <= 1024; k <<= 1) {
        for (int j = k >> 1; j > 0; j >>= 1) {
            __syncthreads();
            int l = t ^ j;
            if (l > t) {
                float si = s[t], sl = s[l];
                int   ii = id[t], il = id[l];
                bool iFirst = (si > sl) || (si == sl && ii < il);
                bool doSwap = ((t & k) == 0) ? (!iFirst) : iFirst;
                if (doSwap) { s[t] = sl; s[l] = si; id[t] = il; id[l] = ii; }
            }
        }
    }
    __syncthreads();
    if (t < KK) {
        snode[b * KK + t] = b * NPGc + id[t];
        sw[b * KK + t]    = tanhf(s[t]);
    }
}

// ---------------- pool: partial max over 63-row slices, 8 blocks/graph ----------

__global__ __launch_bounds__(256) void k_pool(
        const int* __restrict__ snode, const float* __restrict__ sw,
        const float* __restrict__ h2, float* __restrict__ part) {
    __shared__ int   sn[64];
    __shared__ float sv[64];
    int b = blockIdx.x >> 3;
    int j = blockIdx.x & 7;
    int t = threadIdx.x;
    int q0 = j * 63;
    int cnt = min(63, KK - q0);
    if (t < cnt) {
        sn[t] = snode[b * KK + q0 + t];
        sv[t] = sw[b * KK + q0 + t];
    }
    __syncthreads();
    float m = -FLT_MAX;
    for (int q = 0; q < cnt; ++q)
        m = fmaxf(m, h2[sn[q] * HH + t] * sv[q]);
    part[blockIdx.x * 256 + t] = m;
}

__global__ __launch_bounds__(256) void k_out(
        const float* __restrict__ part, const int* __restrict__ flag,
        void* __restrict__ out) {
    int b = blockIdx.x, t = threadIdx.x;
    float r = part[(b * 8 + 0) * 256 + t];
#pragma unroll
    for (int j = 1; j < 8; ++j)
        r = fmaxf(r, part[(b * 8 + j) * 256 + t]);
    if (*flag) ((float*)out)[b * HH + t] = r;
    else       ((bf16*)out)[b * HH + t] = __float2bfloat16(r);
}

// ---------------- launch ----------------

extern "C" void kernel_launch(void* const* d_in, const int* in_sizes, int n_in,
                              void* d_out, int out_size, void* d_ws, size_t ws_size,
                              hipStream_t stream) {
    const int*  x    = (const int*)d_in[0];
    const int*  esrc = (const int*)d_in[1];
    const int*  edst = esrc + EE;
    const void* W1   = d_in[3];
    const void* b1   = d_in[4];
    const void* W2   = d_in[5];
    const void* b2   = d_in[6];
    const void* Wrel = d_in[7];
    const void* brel = d_in[8];
    const void* Wroot= d_in[9];

    char* w = (char*)d_ws;
    size_t off = 0;
    auto carve = [&](size_t bytes) -> void* {
        void* p = w + off;
        off = (off + bytes + 255) & ~(size_t)255;
        return p;
    };
    int*    flag    = (int*)   carve(256);
    int*    deg     = (int*)   carve((size_t)NN * 4);
    int*    partial = (int*)   carve((size_t)NN * 4);
    int*    bsums   = (int*)   carve(256 * 4);
    int*    offsets = (int*)   carve((size_t)(NN + 1) * 4);
    int*    eidx    = (int*)   carve((size_t)EE * 4);
    int*    pose    = (int*)   carve((size_t)EE * 4);
    float*  dinv    = (float*) carve((size_t)NN * 4);
    float*  trel    = (float*) carve((size_t)NN * 4);
    float*  troot   = (float*) carve((size_t)NN * 4);
    int*    snode   = (int*)   carve((size_t)BB * KK * 4);
    float*  swb     = (float*) carve((size_t)BB * KK * 4);
    float*  part    = (float*) carve((size_t)BB * 8 * 256 * 4);
    short8* Bf      = (short8*)carve((size_t)3 * 8192 * 16);  // W2 bf16x3 B-frags
    float*  bufA    = (float*) carve((size_t)NN * HH * 4);    // h1
    float*  bufB    = (float*) carve((size_t)NN * HH * 4);    // h2
    (void)ws_size; (void)in_sizes; (void)n_in; (void)out_size;

    const int NB   = (NN + 255) / 256;     // 196
    const int EBLK = (EE + 255) / 256;     // 1172
    const int NGB  = (NN + 3) / 4;         // 12500
    const int GB   = (NN + GR - 1) / GR;   // 1563

    hipMemsetAsync(deg, 0, (size_t)NN * 4, stream);
    k_count     <<<EBLK + 1, 256, 0, stream>>>(edst, deg, pose,
                                               (const unsigned int*)W1, flag);
    k_prep      <<<32, 256, 0, stream>>>(W2, flag, Bf);
    k_scan_block<<<NB, 256, 0, stream>>>(deg, partial, bsums);
    k_finalize  <<<NB, 256, 0, stream>>>(deg, partial, bsums, offsets, dinv);
    k_fill      <<<EBLK, 256, 0, stream>>>(esrc, edst, offsets, pose, eidx);

    k_layer1    <<<NGB, 256, 0, stream>>>(x, offsets, eidx, dinv, W1, b1, flag, bufA);
    k_gemm2     <<<GB, 256, 0, stream>>>(offsets, eidx, dinv, bufA,
                                         W2, b2, Wrel, Wroot, flag,
                                         Bf, bufB, trel, troot);
    k_topk      <<<BB, 1024, 0, stream>>>(offsets, eidx, trel, troot, brel, flag,
                                          snode, swb);
    k_pool      <<<BB * 8, 256, 0, stream>>>(snode, swb, bufB, part);
    k_out       <<<BB, 256, 0, stream>>>(part, flag, d_out);
}

// Round 17
// 233.603 us; speedup vs baseline: 1.0626x; 1.0389x over previous
//
#include <hip/hip_runtime.h>
#include <hip/hip_bf16.h>
#include <float.h>
#include <math.h>

#define NN   50000
#define BB   50
#define NPGc 1000
#define EE   300000
#define HH   256
#define FIN  79
#define KK   500
#define GR   32      // gemm rows per block
#define APAD 264     // gemm2 A-plane LDS row stride in ushorts (256 + 8 pad)

typedef __hip_bfloat16 bf16;
typedef float v2f __attribute__((ext_vector_type(2)));
typedef short short8 __attribute__((ext_vector_type(8)));
typedef float f32x4 __attribute__((ext_vector_type(4)));

__device__ __forceinline__ float bfbits(unsigned short h) {
    return __uint_as_float(((unsigned int)h) << 16);
}
__device__ __forceinline__ float ldf(const void* p, int i, bool f32) {
    return f32 ? ((const float*)p)[i] : bfbits(((const unsigned short*)p)[i]);
}
__device__ __forceinline__ float4 ldf4(const void* p, int i, bool f32) {
    if (f32) return ((const float4*)p)[i >> 2];
    ushort4 u = ((const ushort4*)p)[i >> 2];
    return make_float4(bfbits(u.x), bfbits(u.y), bfbits(u.z), bfbits(u.w));
}
__device__ __forceinline__ int   rli(int v, int q) {
    return __builtin_amdgcn_readlane(v, q);
}
__device__ __forceinline__ float rlf(float v, int q) {
    return __int_as_float(__builtin_amdgcn_readlane(__float_as_int(v), q));
}
// fp32 -> 3 bf16 planes (RNE at each step; residuals exact) ~2^-24 total error
__device__ __forceinline__ void split3(float a, unsigned short& h,
                                       unsigned short& m, unsigned short& l) {
    unsigned int u = __float_as_uint(a);
    h = (unsigned short)((u + 0x7FFFu + ((u >> 16) & 1u)) >> 16);
    float r1 = a - bfbits(h);
    u = __float_as_uint(r1);
    m = (unsigned short)((u + 0x7FFFu + ((u >> 16) & 1u)) >> 16);
    float r2 = r1 - bfbits(m);
    u = __float_as_uint(r2);
    l = (unsigned short)((u + 0x7FFFu + ((u >> 16) & 1u)) >> 16);
}

// ---------------- count (+ dtype detect in the extra block) ----------------
// Also records each edge's intra-bucket position so k_fill needs no atomics.

__global__ void k_count(const int* __restrict__ edst, int* __restrict__ deg,
                        int* __restrict__ pose,
                        const unsigned int* __restrict__ w1, int* __restrict__ flag) {
    int t = threadIdx.x;
    if (blockIdx.x == gridDim.x - 1) {
        __shared__ int sm[256];
        int c = 0;
        for (int i = t; i < 10112; i += 256) {
            unsigned int e = (w1[i] >> 7) & 0xFFu;
            c += (e >= 128u) ? 1 : 0;
        }
        sm[t] = c;
        __syncthreads();
        for (int off = 128; off > 0; off >>= 1) {
            if (t < off) sm[t] += sm[t + off];
            __syncthreads();
        }
        if (t == 0) flag[0] = (sm[0] > 500) ? 1 : 0;
        return;
    }
    int e = blockIdx.x * 256 + t;
    if (e < EE) pose[e] = atomicAdd(&deg[edst[e]], 1);
}

// ---------------- prep: W2 -> 3 bf16 planes in B-fragment order ----------------

__global__ void k_prep(const void* __restrict__ W2, const int* __restrict__ flag,
                       short8* __restrict__ Bf) {
    if (*flag == 0) return;            // bf16-input path: unused
    const float* W = (const float*)W2;
    int g = blockIdx.x * 256 + threadIdx.x;   // 0..8191
    int lane = g & 63;
    int pair = g >> 6;                 // 0..127
    int ks = pair & 7, nt = pair >> 3;
    int quad = lane >> 4, l15 = lane & 15;
    short8 hv, mv, lv;
#pragma unroll
    for (int j = 0; j < 8; ++j) {
        float a = W[(ks * 32 + quad * 8 + j) * HH + nt * 16 + l15];
        unsigned short h, m, l;
        split3(a, h, m, l);
        hv[j] = (short)h; mv[j] = (short)m; lv[j] = (short)l;
    }
    int e = (nt * 8 + ks) * 64 + lane;
    Bf[e]         = hv;
    Bf[e + 8192]  = mv;
    Bf[e + 16384] = lv;
}

// ---------------- CSR scan ----------------

__global__ void k_scan_block(const int* __restrict__ deg, int* __restrict__ partial,
                             int* __restrict__ bsums) {
    __shared__ int sm[256];
    int t = threadIdx.x;
    int i = blockIdx.x * 256 + t;
    int v = (i < NN) ? deg[i] : 0;
    sm[t] = v;
    __syncthreads();
    for (int off = 1; off < 256; off <<= 1) {
        int u = (t >= off) ? sm[t - off] : 0;
        __syncthreads();
        sm[t] += u;
        __syncthreads();
    }
    if (i < NN) partial[i] = sm[t];
    if (t == 255) bsums[blockIdx.x] = sm[255];
}

__global__ void k_finalize(const int* __restrict__ deg, const int* __restrict__ partial,
                           const int* __restrict__ bsums, int* __restrict__ offsets,
                           float* __restrict__ dinv) {
    __shared__ int sm[256];
    int b = blockIdx.x;
    int t = threadIdx.x;
    sm[t] = (t < b) ? bsums[t] : 0;
    __syncthreads();
    for (int off = 128; off > 0; off >>= 1) {
        if (t < off) sm[t] += sm[t + off];
        __syncthreads();
    }
    int base = sm[0];
    int i = b * 256 + t;
    if (i >= NN) return;
    int incl = partial[i] + base;
    offsets[i] = incl - deg[i];
    if (i == NN - 1) offsets[NN] = incl;
    dinv[i] = rsqrtf((float)(deg[i] + 1));   // +1 self-loop
}

__global__ void k_fill(const int* __restrict__ esrc, const int* __restrict__ edst,
                       const int* __restrict__ offsets, const int* __restrict__ pose,
                       int* __restrict__ eidx) {
    int e = blockIdx.x * blockDim.x + threadIdx.x;
    if (e < EE) {
        int d = edst[e];
        eidx[offsets[d] + pose[e]] = esrc[e];
    }
}

// ---------------- layer 1: h1 = relu(GCN(one_hot(x), W1, b1)) ----------------
// r14 form: readlane broadcast + 4-wide load pipeline + serial remainder
// (r16's zero-pad variant regressed: padded slots issue real loads).

__global__ __launch_bounds__(256) void k_layer1(
        const int* __restrict__ x, const int* __restrict__ offsets,
        const int* __restrict__ eidx, const float* __restrict__ dinv,
        const void* __restrict__ W1, const void* __restrict__ b1,
        const int* __restrict__ flag, float* __restrict__ h1) {
    bool f32 = (*flag != 0);
    int node = blockIdx.x * 4 + (threadIdx.x >> 6);
    int lane = threadIdx.x & 63;
    int ch = lane * 4;
    if (node >= NN) return;
    int beg = offsets[node], end = offsets[node + 1];
    float4 acc = make_float4(0.f, 0.f, 0.f, 0.f);
    for (int base = beg; base < end; base += 64) {
        int cnt = min(64, end - base);
        int p  = base + ((lane < cnt) ? lane : 0);
        int sl = eidx[p];
        int xl = x[sl];
        float dvl = dinv[sl];
        int q = 0;
        for (; q + 4 <= cnt; q += 4) {
            int x0 = rli(xl, q), x1 = rli(xl, q + 1);
            int x2 = rli(xl, q + 2), x3 = rli(xl, q + 3);
            float d0 = rlf(dvl, q), d1 = rlf(dvl, q + 1);
            float d2 = rlf(dvl, q + 2), d3 = rlf(dvl, q + 3);
            float4 w0 = ldf4(W1, x0 * HH + ch, f32);
            float4 w1 = ldf4(W1, x1 * HH + ch, f32);
            float4 w2 = ldf4(W1, x2 * HH + ch, f32);
            float4 w3 = ldf4(W1, x3 * HH + ch, f32);
            acc.x += d0 * w0.x; acc.y += d0 * w0.y; acc.z += d0 * w0.z; acc.w += d0 * w0.w;
            acc.x += d1 * w1.x; acc.y += d1 * w1.y; acc.z += d1 * w1.z; acc.w += d1 * w1.w;
            acc.x += d2 * w2.x; acc.y += d2 * w2.y; acc.z += d2 * w2.z; acc.w += d2 * w2.w;
            acc.x += d3 * w3.x; acc.y += d3 * w3.y; acc.z += d3 * w3.z; acc.w += d3 * w3.w;
        }
        for (; q < cnt; ++q) {
            int xs   = rli(xl, q);
            float dv = rlf(dvl, q);
            float4 w = ldf4(W1, xs * HH + ch, f32);
            acc.x += dv * w.x; acc.y += dv * w.y; acc.z += dv * w.z; acc.w += dv * w.w;
        }
    }
    float di = dinv[node];
    float d2 = di * di;
    float4 ws = ldf4(W1, x[node] * HH + ch, f32);
    float4 bb = ldf4(b1, ch, f32);
    float4 o;
    o.x = fmaxf(di * acc.x + d2 * ws.x + bb.x, 0.f);
    o.y = fmaxf(di * acc.y + d2 * ws.y + bb.y, 0.f);
    o.z = fmaxf(di * acc.z + d2 * ws.z + bb.z, 0.f);
    o.w = fmaxf(di * acc.w + d2 * ws.w + bb.w, 0.f);
    ((float4*)h1)[(node * HH + ch) >> 2] = o;
}

// ---------------- fused agg2 + gemm2: h2 = relu((A_norm @ h1) @ W2 + b2) ----------
// fp32 path: bf16x3-split MFMA + r14 batched metadata preload + r17 ROW-
// INTERLEAVED gather: the 8 independent row accumulators advance group-major
// (for q: for rr:), so up to 32 h1-loads are in flight instead of 4. Per-row
// op order unchanged -> bit-identical to r14. deg>64 tail uses the serial path.

__global__ __launch_bounds__(256) void k_gemm2(
        const int* __restrict__ offsets, const int* __restrict__ eidx,
        const float* __restrict__ dinv, const float* __restrict__ h1,
        const void* __restrict__ W2, const void* __restrict__ b2,
        const void* __restrict__ Wrel, const void* __restrict__ Wroot,
        const int* __restrict__ flag, const short8* __restrict__ Bf,
        float* __restrict__ Y, float* __restrict__ trel, float* __restrict__ troot) {
    __shared__ __align__(16) char lds[3 * GR * APAD * 2 + 1024];  // 51712 B
    bool f32 = (*flag != 0);
    int t = threadIdx.x;
    int lane = t & 63;
    int rg = t >> 6;
    int b = blockIdx.x;
    int grp = (b < 1560) ? ((b & 7) * 195 + (b >> 3)) : b;
    int r0 = grp * GR;
    int ch = lane * 4;
    const float4* H4 = (const float4*)h1;

    if (f32) {
        unsigned short* pH = (unsigned short*)lds;
        unsigned short* pM = pH + GR * APAD;
        unsigned short* pL = pM + GR * APAD;
        float* redR = (float*)(lds + 3 * GR * APAD * 2);
        float* redO = redR + 128;

        // ---- batched metadata preload for the 8 rows ----
        int begs[8], ends[8], cnt8[8];
#pragma unroll
        for (int rr = 0; rr < 8; ++rr) {
            int row = r0 + rg * 8 + rr;
            int rc = min(row, NN - 1);
            begs[rr] = offsets[rc];
            ends[rr] = offsets[rc + 1];
            cnt8[rr] = (row < NN) ? min(64, ends[rr] - begs[rr]) : 0;
        }
        int   sl8[8];
        float dv8[8];
#pragma unroll
        for (int rr = 0; rr < 8; ++rr) {
            int c0 = max(cnt8[rr], 1);
            int p = begs[rr] + ((lane < c0) ? lane : 0);
            p = min(p, EE - 1);
            sl8[rr] = eidx[p];
        }
#pragma unroll
        for (int rr = 0; rr < 8; ++rr) dv8[rr] = dinv[sl8[rr]];

        int maxc = 0;
#pragma unroll
        for (int rr = 0; rr < 8; ++rr) maxc = max(maxc, cnt8[rr]);

        // ---- interleaved first-chunk gather: group-major over 8 rows ----
        float4 acc8[8];
#pragma unroll
        for (int rr = 0; rr < 8; ++rr) acc8[rr] = make_float4(0.f, 0.f, 0.f, 0.f);

        for (int q = 0; q < maxc; q += 4) {
#pragma unroll
            for (int rr = 0; rr < 8; ++rr) {
                int cnt = cnt8[rr];
                if (q < cnt) {                       // wave-uniform branch
                    int i1 = min(q + 1, cnt - 1);
                    int i2 = min(q + 2, cnt - 1);
                    int i3 = min(q + 3, cnt - 1);
                    int s0 = rli(sl8[rr], q),  s1 = rli(sl8[rr], i1);
                    int s2 = rli(sl8[rr], i2), s3 = rli(sl8[rr], i3);
                    float d0 = rlf(dv8[rr], q);
                    float d1 = (q + 1 < cnt) ? rlf(dv8[rr], i1) : 0.f;
                    float d2 = (q + 2 < cnt) ? rlf(dv8[rr], i2) : 0.f;
                    float d3 = (q + 3 < cnt) ? rlf(dv8[rr], i3) : 0.f;
                    float4 v0 = H4[(s0 * HH + ch) >> 2];
                    float4 v1 = H4[(s1 * HH + ch) >> 2];
                    float4 v2 = H4[(s2 * HH + ch) >> 2];
                    float4 v3 = H4[(s3 * HH + ch) >> 2];
                    float4 a = acc8[rr];
                    a.x += d0 * v0.x; a.y += d0 * v0.y; a.z += d0 * v0.z; a.w += d0 * v0.w;
                    a.x += d1 * v1.x; a.y += d1 * v1.y; a.z += d1 * v1.z; a.w += d1 * v1.w;
                    a.x += d2 * v2.x; a.y += d2 * v2.y; a.z += d2 * v2.z; a.w += d2 * v2.w;
                    a.x += d3 * v3.x; a.y += d3 * v3.y; a.z += d3 * v3.z; a.w += d3 * v3.w;
                    acc8[rr] = a;
                }
            }
        }

        // ---- rare deg>64 tail chunks (serial), then normalize + split + store ----
        for (int rr = 0; rr < 8; ++rr) {
            int row = r0 + rg * 8 + rr;
            float4 acc = acc8[rr];
            if (row < NN) {
                for (int base = begs[rr] + 64; base < ends[rr]; base += 64) {
                    int cnt = min(64, ends[rr] - base);
                    int p = base + ((lane < cnt) ? lane : 0);
                    int sl = eidx[p];
                    float dvl = dinv[sl];
                    for (int q = 0; q < cnt; ++q) {
                        int s    = rli(sl, q);
                        float dv = rlf(dvl, q);
                        float4 v = H4[(s * HH + ch) >> 2];
                        acc.x += dv * v.x; acc.y += dv * v.y;
                        acc.z += dv * v.z; acc.w += dv * v.w;
                    }
                }
                float di = dinv[row];
                float d2 = di * di;
                float4 v = H4[(row * HH + ch) >> 2];
                acc.x = di * acc.x + d2 * v.x;
                acc.y = di * acc.y + d2 * v.y;
                acc.z = di * acc.z + d2 * v.z;
                acc.w = di * acc.w + d2 * v.w;
            } else {
                acc = make_float4(0.f, 0.f, 0.f, 0.f);
            }
            ushort4 hv, mv, lv;
            split3(acc.x, hv.x, mv.x, lv.x);
            split3(acc.y, hv.y, mv.y, lv.y);
            split3(acc.z, hv.z, mv.z, lv.z);
            split3(acc.w, hv.w, mv.w, lv.w);
            int base = (rg * 8 + rr) * APAD + ch;
            *(ushort4*)(pH + base) = hv;
            *(ushort4*)(pM + base) = mv;
            *(ushort4*)(pL + base) = lv;
        }
        __syncthreads();   // cross-wave: A-frag reads span all 32 rows

        // ---- compute: 8 k-steps x (2 mt x 4 nt) tiles x 6 split products ----
        int quad = lane >> 4, l15 = lane & 15;
        int nt0 = rg * 4;
        f32x4 acc[2][4];
#pragma unroll
        for (int mt = 0; mt < 2; ++mt)
#pragma unroll
            for (int nt = 0; nt < 4; ++nt) acc[mt][nt] = (f32x4)0.f;

#pragma unroll
        for (int ks = 0; ks < 8; ++ks) {
            short8 aH[2], aM[2], aL[2];
#pragma unroll
            for (int mt = 0; mt < 2; ++mt) {
                int boff = (mt * 16 + l15) * APAD + ks * 32 + quad * 8;
                aH[mt] = *(const short8*)(pH + boff);
                aM[mt] = *(const short8*)(pM + boff);
                aL[mt] = *(const short8*)(pL + boff);
            }
            short8 bH[4], bM[4], bL[4];
#pragma unroll
            for (int nt = 0; nt < 4; ++nt) {
                int e = ((nt0 + nt) * 8 + ks) * 64 + lane;
                bH[nt] = Bf[e];
                bM[nt] = Bf[e + 8192];
                bL[nt] = Bf[e + 16384];
            }
#pragma unroll
            for (int mt = 0; mt < 2; ++mt)
#pragma unroll
                for (int nt = 0; nt < 4; ++nt)
                    acc[mt][nt] = __builtin_amdgcn_mfma_f32_16x16x32_bf16(aH[mt], bH[nt], acc[mt][nt], 0, 0, 0);
#pragma unroll
            for (int mt = 0; mt < 2; ++mt)
#pragma unroll
                for (int nt = 0; nt < 4; ++nt)
                    acc[mt][nt] = __builtin_amdgcn_mfma_f32_16x16x32_bf16(aM[mt], bH[nt], acc[mt][nt], 0, 0, 0);
#pragma unroll
            for (int mt = 0; mt < 2; ++mt)
#pragma unroll
                for (int nt = 0; nt < 4; ++nt)
                    acc[mt][nt] = __builtin_amdgcn_mfma_f32_16x16x32_bf16(aH[mt], bM[nt], acc[mt][nt], 0, 0, 0);
#pragma unroll
            for (int mt = 0; mt < 2; ++mt)
#pragma unroll
                for (int nt = 0; nt < 4; ++nt)
                    acc[mt][nt] = __builtin_amdgcn_mfma_f32_16x16x32_bf16(aL[mt], bH[nt], acc[mt][nt], 0, 0, 0);
#pragma unroll
            for (int mt = 0; mt < 2; ++mt)
#pragma unroll
                for (int nt = 0; nt < 4; ++nt)
                    acc[mt][nt] = __builtin_amdgcn_mfma_f32_16x16x32_bf16(aH[mt], bL[nt], acc[mt][nt], 0, 0, 0);
#pragma unroll
            for (int mt = 0; mt < 2; ++mt)
#pragma unroll
                for (int nt = 0; nt < 4; ++nt)
                    acc[mt][nt] = __builtin_amdgcn_mfma_f32_16x16x32_bf16(aM[mt], bM[nt], acc[mt][nt], 0, 0, 0);
        }

        // ---- epilogue: relu + store + fused scorer dots ----
        const float* b2f = (const float*)b2;
        const float* wrf = (const float*)Wrel;
        const float* wof = (const float*)Wroot;
        float b2v[4], wrv[4], wov[4];
#pragma unroll
        for (int nt = 0; nt < 4; ++nt) {
            int col = (nt0 + nt) * 16 + l15;
            b2v[nt] = b2f[col]; wrv[nt] = wrf[col]; wov[nt] = wof[col];
        }
#pragma unroll
        for (int mt = 0; mt < 2; ++mt) {
#pragma unroll
            for (int r = 0; r < 4; ++r) {
                int row = r0 + mt * 16 + quad * 4 + r;
                float sr = 0.f, so = 0.f;
#pragma unroll
                for (int nt = 0; nt < 4; ++nt) {
                    float y = fmaxf(acc[mt][nt][r] + b2v[nt], 0.f);
                    if (row < NN) Y[row * HH + (nt0 + nt) * 16 + l15] = y;
                    sr += y * wrv[nt];
                    so += y * wov[nt];
                }
#pragma unroll
                for (int off = 1; off < 16; off <<= 1) {
                    sr += __shfl_xor(sr, off, 64);
                    so += __shfl_xor(so, off, 64);
                }
                if (l15 == 0) {
                    redR[(mt * 16 + quad * 4 + r) * 4 + rg] = sr;
                    redO[(mt * 16 + quad * 4 + r) * 4 + rg] = so;
                }
            }
        }
        __syncthreads();
        if (t < GR) {
            int row = r0 + t;
            if (row < NN) {
                trel[row]  = redR[t * 4] + redR[t * 4 + 1] + redR[t * 4 + 2] + redR[t * 4 + 3];
                troot[row] = redO[t * 4] + redO[t * 4 + 1] + redO[t * 4 + 2] + redO[t * 4 + 3];
            }
        }
        return;
    }

    // ---------------- bf16-input fallback: r12 pk-fma path ----------------
    {
        float (*As)[HH] = (float (*)[HH])lds;
        int c4 = lane;
        for (int rr = 0; rr < 8; ++rr) {
            int row = r0 + rg * 8 + rr;
            float4 acc = make_float4(0.f, 0.f, 0.f, 0.f);
            if (row < NN) {
                int beg = offsets[row], end = offsets[row + 1];
                for (int base = beg; base < end; base += 64) {
                    int cnt = min(64, end - base);
                    int p  = base + ((lane < cnt) ? lane : 0);
                    int sl = eidx[p];
                    float dvl = dinv[sl];
                    for (int q = 0; q < cnt; ++q) {
                        int s    = rli(sl, q);
                        float dv = rlf(dvl, q);
                        float4 v = H4[(s * HH + ch) >> 2];
                        acc.x += dv * v.x; acc.y += dv * v.y;
                        acc.z += dv * v.z; acc.w += dv * v.w;
                    }
                }
                float di = dinv[row];
                float d2 = di * di;
                float4 v = H4[(row * HH + ch) >> 2];
                acc.x = di * acc.x + d2 * v.x;
                acc.y = di * acc.y + d2 * v.y;
                acc.z = di * acc.z + d2 * v.z;
                acc.w = di * acc.w + d2 * v.w;
            }
            *(float4*)&As[rg * 8 + rr][ch] = acc;
        }
        // no barrier: tile slice is wave-private

        v2f accL[8], accH[8];
#pragma unroll
        for (int rr = 0; rr < 8; ++rr) { accL[rr] = (v2f)0.f; accH[rr] = (v2f)0.f; }
        const unsigned short* W = (const unsigned short*)W2;
        ushort4 u0 = *(const ushort4*)&W[0 * HH + c4 * 4];
        ushort4 u1 = *(const ushort4*)&W[1 * HH + c4 * 4];
        ushort4 u2 = *(const ushort4*)&W[2 * HH + c4 * 4];
        ushort4 u3 = *(const ushort4*)&W[3 * HH + c4 * 4];
        for (int k = 0; k < 256; k += 4) {
            ushort4 m0, m1, m2, m3;
            int kn = (k + 4) & 255;
            m0 = *(const ushort4*)&W[(kn + 0) * HH + c4 * 4];
            m1 = *(const ushort4*)&W[(kn + 1) * HH + c4 * 4];
            m2 = *(const ushort4*)&W[(kn + 2) * HH + c4 * 4];
            m3 = *(const ushort4*)&W[(kn + 3) * HH + c4 * 4];
            v2f w0L = {bfbits(u0.x), bfbits(u0.y)}, w0H = {bfbits(u0.z), bfbits(u0.w)};
            v2f w1L = {bfbits(u1.x), bfbits(u1.y)}, w1H = {bfbits(u1.z), bfbits(u1.w)};
            v2f w2L = {bfbits(u2.x), bfbits(u2.y)}, w2H = {bfbits(u2.z), bfbits(u2.w)};
            v2f w3L = {bfbits(u3.x), bfbits(u3.y)}, w3H = {bfbits(u3.z), bfbits(u3.w)};
#pragma unroll
            for (int rr = 0; rr < 8; ++rr) {
                float4 a = *(const float4*)&As[rg * 8 + rr][k];
                v2f ax = a.x, ay = a.y, az = a.z, aw = a.w;
                accL[rr] += ax * w0L; accH[rr] += ax * w0H;
                accL[rr] += ay * w1L; accH[rr] += ay * w1H;
                accL[rr] += az * w2L; accH[rr] += az * w2H;
                accL[rr] += aw * w3L; accH[rr] += aw * w3H;
            }
            u0 = m0; u1 = m1; u2 = m2; u3 = m3;
        }
        float4 bb = ldf4(b2, c4 * 4, f32);
        float4 wr = ldf4(Wrel, c4 * 4, f32);
        float4 wo = ldf4(Wroot, c4 * 4, f32);
#pragma unroll
        for (int rr = 0; rr < 8; ++rr) {
            int row = r0 + rg * 8 + rr;
            float4 y;
            y.x = fmaxf(accL[rr].x + bb.x, 0.f);
            y.y = fmaxf(accL[rr].y + bb.y, 0.f);
            y.z = fmaxf(accH[rr].x + bb.z, 0.f);
            y.w = fmaxf(accH[rr].y + bb.w, 0.f);
            if (row < NN)
                *(float4*)&Y[row * HH + c4 * 4] = y;
            float sr = y.x * wr.x + y.y * wr.y + y.z * wr.z + y.w * wr.w;
            float so = y.x * wo.x + y.y * wo.y + y.z * wo.z + y.w * wo.w;
#pragma unroll
            for (int off = 32; off > 0; off >>= 1) {
                sr += __shfl_xor(sr, off, 64);
                so += __shfl_xor(so, off, 64);
            }
            if (c4 == 0 && row < NN) { trel[row] = sr; troot[row] = so; }
        }
    }
}

// ---------------- score -> per-graph top-k (selection only) ----------------

__global__ __launch_bounds__(1024) void k_topk(
        const int* __restrict__ offsets, const int* __restrict__ eidx,
        const float* __restrict__ trel, const float* __restrict__ troot,
        const void* __restrict__ brel, const int* __restrict__ flag,
        int* __restrict__ snode, float* __restrict__ sw) {
    __shared__ float s[1024];
    __shared__ int   id[1024];
    bool f32 = (*flag != 0);
    int b = blockIdx.x, t = threadIdx.x;
    float br = ldf(brel, 0, f32);
    if (t < NPGc) {
        int node = b * NPGc + t;
        float sc = br + troot[node];
        int beg = offsets[node], end = offsets[node + 1];
        for (int p = beg; p < end; ++p) sc += trel[eidx[p]];
        s[t] = sc; id[t] = t;
    } else { s[t] = -FLT_MAX; id[t] = 0x7FFFFFFF; }
    for (int k = 2; k <= 1024; k <<= 1) {
        for (int j = k >> 1; j > 0; j >>= 1) {
            __syncthreads();
            int l = t ^ j;
            if (l > t) {
                float si = s[t], sl = s[l];
                int   ii = id[t], il = id[l];
                bool iFirst = (si > sl) || (si == sl && ii < il);
                bool doSwap = ((t & k) == 0) ? (!iFirst) : iFirst;
                if (doSwap) { s[t] = sl; s[l] = si; id[t] = il; id[l] = ii; }
            }
        }
    }
    __syncthreads();
    if (t < KK) {
        snode[b * KK + t] = b * NPGc + id[t];
        sw[b * KK + t]    = tanhf(s[t]);
    }
}

// ---------------- pool: partial max over 63-row slices, 8 blocks/graph ----------

__global__ __launch_bounds__(256) void k_pool(
        const int* __restrict__ snode, const float* __restrict__ sw,
        const float* __restrict__ h2, float* __restrict__ part) {
    __shared__ int   sn[64];
    __shared__ float sv[64];
    int b = blockIdx.x >> 3;
    int j = blockIdx.x & 7;
    int t = threadIdx.x;
    int q0 = j * 63;
    int cnt = min(63, KK - q0);
    if (t < cnt) {
        sn[t] = snode[b * KK + q0 + t];
        sv[t] = sw[b * KK + q0 + t];
    }
    __syncthreads();
    float m = -FLT_MAX;
    for (int q = 0; q < cnt; ++q)
        m = fmaxf(m, h2[sn[q] * HH + t] * sv[q]);
    part[blockIdx.x * 256 + t] = m;
}

__global__ __launch_bounds__(256) void k_out(
        const float* __restrict__ part, const int* __restrict__ flag,
        void* __restrict__ out) {
    int b = blockIdx.x, t = threadIdx.x;
    float r = part[(b * 8 + 0) * 256 + t];
#pragma unroll
    for (int j = 1; j < 8; ++j)
        r = fmaxf(r, part[(b * 8 + j) * 256 + t]);
    if (*flag) ((float*)out)[b * HH + t] = r;
    else       ((bf16*)out)[b * HH + t] = __float2bfloat16(r);
}

// ---------------- launch ----------------

extern "C" void kernel_launch(void* const* d_in, const int* in_sizes, int n_in,
                              void* d_out, int out_size, void* d_ws, size_t ws_size,
                              hipStream_t stream) {
    const int*  x    = (const int*)d_in[0];
    const int*  esrc = (const int*)d_in[1];
    const int*  edst = esrc + EE;
    const void* W1   = d_in[3];
    const void* b1   = d_in[4];
    const void* W2   = d_in[5];
    const void* b2   = d_in[6];
    const void* Wrel = d_in[7];
    const void* brel = d_in[8];
    const void* Wroot= d_in[9];

    char* w = (char*)d_ws;
    size_t off = 0;
    auto carve = [&](size_t bytes) -> void* {
        void* p = w + off;
        off = (off + bytes + 255) & ~(size_t)255;
        return p;
    };
    int*    flag    = (int*)   carve(256);
    int*    deg     = (int*)   carve((size_t)NN * 4);
    int*    partial = (int*)   carve((size_t)NN * 4);
    int*    bsums   = (int*)   carve(256 * 4);
    int*    offsets = (int*)   carve((size_t)(NN + 1) * 4);
    int*    eidx    = (int*)   carve((size_t)EE * 4);
    int*    pose    = (int*)   carve((size_t)EE * 4);
    float*  dinv    = (float*) carve((size_t)NN * 4);
    float*  trel    = (float*) carve((size_t)NN * 4);
    float*  troot   = (float*) carve((size_t)NN * 4);
    int*    snode   = (int*)   carve((size_t)BB * KK * 4);
    float*  swb     = (float*) carve((size_t)BB * KK * 4);
    float*  part    = (float*) carve((size_t)BB * 8 * 256 * 4);
    short8* Bf      = (short8*)carve((size_t)3 * 8192 * 16);  // W2 bf16x3 B-frags
    float*  bufA    = (float*) carve((size_t)NN * HH * 4);    // h1
    float*  bufB    = (float*) carve((size_t)NN * HH * 4);    // h2
    (void)ws_size; (void)in_sizes; (void)n_in; (void)out_size;

    const int NB   = (NN + 255) / 256;     // 196
    const int EBLK = (EE + 255) / 256;     // 1172
    const int NGB  = (NN + 3) / 4;         // 12500
    const int GB   = (NN + GR - 1) / GR;   // 1563

    hipMemsetAsync(deg, 0, (size_t)NN * 4, stream);
    k_count     <<<EBLK + 1, 256, 0, stream>>>(edst, deg, pose,
                                               (const unsigned int*)W1, flag);
    k_prep      <<<32, 256, 0, stream>>>(W2, flag, Bf);
    k_scan_block<<<NB, 256, 0, stream>>>(deg, partial, bsums);
    k_finalize  <<<NB, 256, 0, stream>>>(deg, partial, bsums, offsets, dinv);
    k_fill      <<<EBLK, 256, 0, stream>>>(esrc, edst, offsets, pose, eidx);

    k_layer1    <<<NGB, 256, 0, stream>>>(x, offsets, eidx, dinv, W1, b1, flag, bufA);
    k_gemm2     <<<GB, 256, 0, stream>>>(offsets, eidx, dinv, bufA,
                                         W2, b2, Wrel, Wroot, flag,
                                         Bf, bufB, trel, troot);
    k_topk      <<<BB, 1024, 0, stream>>>(offsets, eidx, trel, troot, brel, flag,
                                          snode, swb);
    k_pool      <<<BB * 8, 256, 0, stream>>>(snode, swb, bufB, part);
    k_out       <<<BB, 256, 0, stream>>>(part, flag, d_out);
}